// Round 2
// baseline (843.560 us; speedup 1.0000x reference)
//
#include <hip/hip_runtime.h>
#include <math.h>

#define N_NODES 100000
#define N_EDGES 1600000
#define F_INN   256
#define HID     128
#define NCLS    47

// ---------------- CSR build ----------------
__global__ void k_init(int* cnt, int* cursor) {
    int i = blockIdx.x * blockDim.x + threadIdx.x;
    if (i < N_NODES) { cnt[i] = 0; cursor[i] = 0; }
}

__global__ void k_count(const int* __restrict__ dst, int* cnt) {
    int e = blockIdx.x * blockDim.x + threadIdx.x;
    if (e < N_EDGES) atomicAdd(&cnt[dst[e]], 1);
}

// single-block scan over N_NODES counts -> rowptr, plus dinv = rsqrt(deg+1)
__global__ void k_scan(const int* __restrict__ cnt, int* __restrict__ rowptr,
                       float* __restrict__ dinv) {
    __shared__ int sums[1024];
    int t = threadIdx.x;
    const int CH = (N_NODES + 1023) / 1024;  // 98
    int s = t * CH;
    int e = min(N_NODES, s + CH);
    int local = 0;
    for (int i = s; i < e; i++) local += cnt[i];
    sums[t] = local;
    __syncthreads();
    // Hillis-Steele inclusive scan
    for (int off = 1; off < 1024; off <<= 1) {
        int v = (t >= off) ? sums[t - off] : 0;
        __syncthreads();
        sums[t] += v;
        __syncthreads();
    }
    int run = sums[t] - local;  // exclusive prefix
    for (int i = s; i < e; i++) {
        rowptr[i] = run;
        int c = cnt[i];
        run += c;
        dinv[i] = rsqrtf((float)c + 1.0f);  // +1 self-loop
    }
    if (t == 1023) rowptr[N_NODES] = run;  // == N_EDGES
}

__global__ void k_scatter(const int* __restrict__ src, const int* __restrict__ dst,
                          const int* __restrict__ rowptr, int* cursor,
                          int* __restrict__ eidx) {
    int e = blockIdx.x * blockDim.x + threadIdx.x;
    if (e < N_EDGES) {
        int d = dst[e];
        int pos = rowptr[d] + atomicAdd(&cursor[d], 1);
        eidx[pos] = src[e];
    }
}

// ---------------- GEMM1: Y = (X @ W1) * dinv[row]  (100000x256 @ 256x128) ----
__global__ __launch_bounds__(256) void k_gemm1(const float* __restrict__ X,
                                               const float* __restrict__ W,
                                               const float* __restrict__ dinv,
                                               float* __restrict__ Y) {
    __shared__ __align__(16) float xs[64][17];
    __shared__ __align__(16) float ws[16][128];
    int tid = threadIdx.x;
    int tx = tid & 15, ty = tid >> 4;
    int row0 = blockIdx.x * 64;

    float acc[4][8];
#pragma unroll
    for (int i = 0; i < 4; i++)
#pragma unroll
        for (int j = 0; j < 8; j++) acc[i][j] = 0.f;

    for (int k0 = 0; k0 < F_INN; k0 += 16) {
        {  // stage X tile 64x16
            int r = tid >> 2, c4 = tid & 3;
            int rr = min(row0 + r, N_NODES - 1);
            float4 v = *(const float4*)&X[(size_t)rr * F_INN + k0 + c4 * 4];
            xs[r][c4 * 4 + 0] = v.x; xs[r][c4 * 4 + 1] = v.y;
            xs[r][c4 * 4 + 2] = v.z; xs[r][c4 * 4 + 3] = v.w;
        }
#pragma unroll
        for (int t = 0; t < 2; t++) {  // stage W tile 16x128
            int idx = t * 256 + tid;   // float4 index
            int k = idx >> 5, c4 = idx & 31;
            *(float4*)&ws[k][c4 * 4] = *(const float4*)&W[(size_t)(k0 + k) * HID + c4 * 4];
        }
        __syncthreads();
#pragma unroll
        for (int kk = 0; kk < 16; kk++) {
            float xv[4];
#pragma unroll
            for (int i = 0; i < 4; i++) xv[i] = xs[ty * 4 + i][kk];
            float4 w0 = *(const float4*)&ws[kk][tx * 8];
            float4 w1 = *(const float4*)&ws[kk][tx * 8 + 4];
#pragma unroll
            for (int i = 0; i < 4; i++) {
                acc[i][0] += xv[i] * w0.x; acc[i][1] += xv[i] * w0.y;
                acc[i][2] += xv[i] * w0.z; acc[i][3] += xv[i] * w0.w;
                acc[i][4] += xv[i] * w1.x; acc[i][5] += xv[i] * w1.y;
                acc[i][6] += xv[i] * w1.z; acc[i][7] += xv[i] * w1.w;
            }
        }
        __syncthreads();
    }
#pragma unroll
    for (int i = 0; i < 4; i++) {
        int row = row0 + ty * 4 + i;
        if (row < N_NODES) {
            float s = dinv[row];
            float4 o0 = make_float4(acc[i][0] * s, acc[i][1] * s, acc[i][2] * s, acc[i][3] * s);
            float4 o1 = make_float4(acc[i][4] * s, acc[i][5] * s, acc[i][6] * s, acc[i][7] * s);
            *(float4*)&Y[(size_t)row * HID + tx * 8]     = o0;
            *(float4*)&Y[(size_t)row * HID + tx * 8 + 4] = o1;
        }
    }
}

// ------------- gather1: H = relu(dinv[i]*(y_i + sum_j y_j) + b1), 1 wave/node
__global__ __launch_bounds__(256) void k_gather1(const float* __restrict__ Y,
                                                 const int* __restrict__ rowptr,
                                                 const int* __restrict__ eidx,
                                                 const float* __restrict__ dinv,
                                                 const float* __restrict__ b1,
                                                 float* __restrict__ Hout) {
    int wave = (blockIdx.x * blockDim.x + threadIdx.x) >> 6;
    int lane = threadIdx.x & 63;
    if (wave >= N_NODES) return;
    const float2* yp = (const float2*)Y;
    float2 acc = yp[(size_t)wave * 64 + lane];  // self-loop (y already * dinv[src])
    int beg = rowptr[wave], end = rowptr[wave + 1];
    for (int e = beg; e < end; e++) {
        int j = eidx[e];
        float2 v = yp[(size_t)j * 64 + lane];
        acc.x += v.x; acc.y += v.y;
    }
    float s = dinv[wave];
    float2 b = ((const float2*)b1)[lane];
    float ox = fmaxf(acc.x * s + b.x, 0.f);
    float oy = fmaxf(acc.y * s + b.y, 0.f);
    ((float2*)Hout)[(size_t)wave * 64 + lane] = make_float2(ox, oy);
}

// ------------- GEMM2: Y2 = (H @ W2) * dinv[row]   (N x 128 @ 128 x 47, pad 48)
__global__ __launch_bounds__(256) void k_gemm2(const float* __restrict__ Hin,
                                               const float* __restrict__ W2,
                                               const float* __restrict__ dinv,
                                               float* __restrict__ Y2) {
    __shared__ __align__(16) float ws[128][48];
    int tid = threadIdx.x;
    for (int idx = tid; idx < 128 * 48; idx += 256) {
        int k = idx / 48, c = idx - k * 48;
        ws[k][c] = (c < NCLS) ? W2[k * NCLS + c] : 0.f;
    }
    __syncthreads();
    int row = blockIdx.x * 256 + tid;
    if (row >= N_NODES) return;
    float4 acc[12];
#pragma unroll
    for (int i = 0; i < 12; i++) acc[i] = make_float4(0.f, 0.f, 0.f, 0.f);
    const float4* h4 = (const float4*)&Hin[(size_t)row * HID];
    for (int k4 = 0; k4 < 32; k4++) {
        float4 hv = h4[k4];
#pragma unroll
        for (int u = 0; u < 4; u++) {
            float xv = (u == 0) ? hv.x : (u == 1) ? hv.y : (u == 2) ? hv.z : hv.w;
            int k = k4 * 4 + u;
#pragma unroll
            for (int c = 0; c < 12; c++) {
                float4 w = *(const float4*)&ws[k][c * 4];
                acc[c].x += xv * w.x; acc[c].y += xv * w.y;
                acc[c].z += xv * w.z; acc[c].w += xv * w.w;
            }
        }
    }
    float s = dinv[row];
#pragma unroll
    for (int c = 0; c < 12; c++) {
        float4 o = make_float4(acc[c].x * s, acc[c].y * s, acc[c].z * s, acc[c].w * s);
        *(float4*)&Y2[(size_t)row * 48 + c * 4] = o;
    }
}

// ------------- gather2: Out = dinv[i]*(y2_i + sum_j y2_j) + b2, 1 wave/node --
__global__ __launch_bounds__(256) void k_gather2(const float* __restrict__ Y2,
                                                 const int* __restrict__ rowptr,
                                                 const int* __restrict__ eidx,
                                                 const float* __restrict__ dinv,
                                                 const float* __restrict__ b2,
                                                 float* __restrict__ Out) {
    int wave = (blockIdx.x * blockDim.x + threadIdx.x) >> 6;
    int lane = threadIdx.x & 63;
    if (wave >= N_NODES) return;
    float acc = 0.f;
    if (lane < NCLS) acc = Y2[(size_t)wave * 48 + lane];
    int beg = rowptr[wave], end = rowptr[wave + 1];
    for (int e = beg; e < end; e++) {
        int j = eidx[e];
        if (lane < NCLS) acc += Y2[(size_t)j * 48 + lane];
    }
    if (lane < NCLS) Out[(size_t)wave * NCLS + lane] = acc * dinv[wave] + b2[lane];
}

// ------------- log_softmax rows of 47, in place ------------------------------
__global__ __launch_bounds__(256) void k_logsoftmax(float* __restrict__ Out) {
    int wave = (blockIdx.x * blockDim.x + threadIdx.x) >> 6;
    int lane = threadIdx.x & 63;
    if (wave >= N_NODES) return;
    float v = (lane < NCLS) ? Out[(size_t)wave * NCLS + lane] : -INFINITY;
    float m = v;
#pragma unroll
    for (int off = 32; off >= 1; off >>= 1) m = fmaxf(m, __shfl_xor(m, off, 64));
    float ex = (lane < NCLS) ? __expf(v - m) : 0.f;
    float ssum = ex;
#pragma unroll
    for (int off = 32; off >= 1; off >>= 1) ssum += __shfl_xor(ssum, off, 64);
    float l = __logf(ssum);
    if (lane < NCLS) Out[(size_t)wave * NCLS + lane] = v - m - l;
}

extern "C" void kernel_launch(void* const* d_in, const int* in_sizes, int n_in,
                              void* d_out, int out_size, void* d_ws, size_t ws_size,
                              hipStream_t stream) {
    const float* x   = (const float*)d_in[0];
    const int*   ei  = (const int*)d_in[1];
    const float* W1  = (const float*)d_in[2];
    const float* b1  = (const float*)d_in[3];
    const float* W2  = (const float*)d_in[4];
    const float* b2  = (const float*)d_in[5];
    float* out = (float*)d_out;

    const int* src = ei;             // edge_index[0]
    const int* dst = ei + N_EDGES;   // edge_index[1]

    char* ws = (char*)d_ws;
    float* y      = (float*)(ws + 0);                         // N*128 f32  (51.2 MB)
    float* h      = (float*)(ws + 51200000);                  // N*128 f32  (51.2 MB)
    float* y2     = (float*)(ws + 102400000);                 // N*48  f32  (19.2 MB)
    float* dinv   = (float*)(ws + 121600000);                 // N f32
    int*   cnt    = (int*)  (ws + 122000000);                 // N int
    int*   cursor = (int*)  (ws + 122400000);                 // N int
    int*   rowptr = (int*)  (ws + 122800000);                 // N+1 int
    int*   eidx   = (int*)  (ws + 123200016);                 // E int (6.4 MB)

    // CSR build
    k_init<<<(N_NODES + 255) / 256, 256, 0, stream>>>(cnt, cursor);
    k_count<<<(N_EDGES + 255) / 256, 256, 0, stream>>>(dst, cnt);
    k_scan<<<1, 1024, 0, stream>>>(cnt, rowptr, dinv);
    k_scatter<<<(N_EDGES + 255) / 256, 256, 0, stream>>>(src, dst, rowptr, cursor, eidx);

    // layer 1
    k_gemm1<<<(N_NODES + 63) / 64, 256, 0, stream>>>(x, W1, dinv, y);
    k_gather1<<<(N_NODES * 64 + 255) / 256, 256, 0, stream>>>(y, rowptr, eidx, dinv, b1, h);

    // layer 2
    k_gemm2<<<(N_NODES + 255) / 256, 256, 0, stream>>>(h, W2, dinv, y2);
    k_gather2<<<(N_NODES * 64 + 255) / 256, 256, 0, stream>>>(y2, rowptr, eidx, dinv, b2, out);

    // log_softmax
    k_logsoftmax<<<(N_NODES * 64 + 255) / 256, 256, 0, stream>>>(out);
}

// Round 3
// 650.714 us; speedup vs baseline: 1.2964x; 1.2964x over previous
//
#include <hip/hip_runtime.h>
#include <math.h>

#define N_NODES 100000
#define N_EDGES 1600000
#define F_INN   256
#define HID     128
#define NCLS    47

#define SCAN_CHUNK 1024
#define N_SBLOCKS ((N_NODES + SCAN_CHUNK - 1) / SCAN_CHUNK)  // 98

// ---------------- CSR build ----------------
__global__ void k_init(int* cnt, int* cursor) {
    int i = blockIdx.x * blockDim.x + threadIdx.x;
    if (i < N_NODES) { cnt[i] = 0; cursor[i] = 0; }
}

__global__ void k_count(const int* __restrict__ dst, int* cnt) {
    int e = blockIdx.x * blockDim.x + threadIdx.x;
    if (e < N_EDGES) atomicAdd(&cnt[dst[e]], 1);
}

// level-1: per-block (1024 counts) partial sums
__global__ __launch_bounds__(256) void k_scan_part(const int* __restrict__ cnt,
                                                   int* __restrict__ bsum) {
    int b = blockIdx.x, t = threadIdx.x;
    int base = b * SCAN_CHUNK;
    int local = 0;
#pragma unroll
    for (int u = 0; u < 4; u++) {
        int idx = base + u * 256 + t;
        if (idx < N_NODES) local += cnt[idx];
    }
#pragma unroll
    for (int off = 32; off >= 1; off >>= 1) local += __shfl_down(local, off, 64);
    __shared__ int red[4];
    if ((t & 63) == 0) red[t >> 6] = local;
    __syncthreads();
    if (t == 0) bsum[b] = red[0] + red[1] + red[2] + red[3];
}

// level-2: scan the 98 block sums (one small block)
__global__ void k_scan_top(const int* __restrict__ bsum, int* __restrict__ boff) {
    __shared__ int s[128];
    int t = threadIdx.x;
    int v = (t < N_SBLOCKS) ? bsum[t] : 0;
    s[t] = v;
    __syncthreads();
    for (int off = 1; off < 128; off <<= 1) {
        int u = (t >= off) ? s[t - off] : 0;
        __syncthreads();
        s[t] += u;
        __syncthreads();
    }
    if (t < N_SBLOCKS) boff[t] = s[t] - v;  // exclusive
}

// level-3: local scan per block + global offset -> rowptr, dinv
__global__ __launch_bounds__(256) void k_scan_final(const int* __restrict__ cnt,
                                                    const int* __restrict__ boff,
                                                    int* __restrict__ rowptr,
                                                    float* __restrict__ dinv) {
    __shared__ int tsum[256];
    int b = blockIdx.x, t = threadIdx.x;
    int base = b * SCAN_CHUNK + t * 4;
    int c[4];
    int local = 0;
#pragma unroll
    for (int u = 0; u < 4; u++) {
        int idx = base + u;
        c[u] = (idx < N_NODES) ? cnt[idx] : 0;
        local += c[u];
    }
    tsum[t] = local;
    __syncthreads();
    for (int off = 1; off < 256; off <<= 1) {
        int u = (t >= off) ? tsum[t - off] : 0;
        __syncthreads();
        tsum[t] += u;
        __syncthreads();
    }
    int run = boff[b] + tsum[t] - local;  // exclusive prefix for this thread's 4
#pragma unroll
    for (int u = 0; u < 4; u++) {
        int idx = base + u;
        if (idx < N_NODES) {
            rowptr[idx] = run;
            dinv[idx] = rsqrtf((float)c[u] + 1.0f);  // +1 self-loop
            run += c[u];
        }
    }
    if (b == 0 && t == 0) rowptr[N_NODES] = N_EDGES;
}

__global__ void k_scatter(const int* __restrict__ src, const int* __restrict__ dst,
                          const int* __restrict__ rowptr, int* cursor,
                          int* __restrict__ eidx) {
    int e = blockIdx.x * blockDim.x + threadIdx.x;
    if (e < N_EDGES) {
        int d = dst[e];
        int pos = rowptr[d] + atomicAdd(&cursor[d], 1);
        eidx[pos] = src[e];
    }
}

// ---------------- GEMM1: Y = (X @ W1) * dinv[row]  (100000x256 @ 256x128) ----
__global__ __launch_bounds__(256) void k_gemm1(const float* __restrict__ X,
                                               const float* __restrict__ W,
                                               const float* __restrict__ dinv,
                                               float* __restrict__ Y) {
    __shared__ __align__(16) float xs[64][17];
    __shared__ __align__(16) float ws[16][128];
    int tid = threadIdx.x;
    int tx = tid & 15, ty = tid >> 4;
    int row0 = blockIdx.x * 64;

    float acc[4][8];
#pragma unroll
    for (int i = 0; i < 4; i++)
#pragma unroll
        for (int j = 0; j < 8; j++) acc[i][j] = 0.f;

    for (int k0 = 0; k0 < F_INN; k0 += 16) {
        {  // stage X tile 64x16
            int r = tid >> 2, c4 = tid & 3;
            int rr = min(row0 + r, N_NODES - 1);
            float4 v = *(const float4*)&X[(size_t)rr * F_INN + k0 + c4 * 4];
            xs[r][c4 * 4 + 0] = v.x; xs[r][c4 * 4 + 1] = v.y;
            xs[r][c4 * 4 + 2] = v.z; xs[r][c4 * 4 + 3] = v.w;
        }
#pragma unroll
        for (int t = 0; t < 2; t++) {  // stage W tile 16x128
            int idx = t * 256 + tid;   // float4 index
            int k = idx >> 5, c4 = idx & 31;
            *(float4*)&ws[k][c4 * 4] = *(const float4*)&W[(size_t)(k0 + k) * HID + c4 * 4];
        }
        __syncthreads();
#pragma unroll
        for (int kk = 0; kk < 16; kk++) {
            float xv[4];
#pragma unroll
            for (int i = 0; i < 4; i++) xv[i] = xs[ty * 4 + i][kk];
            float4 w0 = *(const float4*)&ws[kk][tx * 8];
            float4 w1 = *(const float4*)&ws[kk][tx * 8 + 4];
#pragma unroll
            for (int i = 0; i < 4; i++) {
                acc[i][0] += xv[i] * w0.x; acc[i][1] += xv[i] * w0.y;
                acc[i][2] += xv[i] * w0.z; acc[i][3] += xv[i] * w0.w;
                acc[i][4] += xv[i] * w1.x; acc[i][5] += xv[i] * w1.y;
                acc[i][6] += xv[i] * w1.z; acc[i][7] += xv[i] * w1.w;
            }
        }
        __syncthreads();
    }
#pragma unroll
    for (int i = 0; i < 4; i++) {
        int row = row0 + ty * 4 + i;
        if (row < N_NODES) {
            float s = dinv[row];
            float4 o0 = make_float4(acc[i][0] * s, acc[i][1] * s, acc[i][2] * s, acc[i][3] * s);
            float4 o1 = make_float4(acc[i][4] * s, acc[i][5] * s, acc[i][6] * s, acc[i][7] * s);
            *(float4*)&Y[(size_t)row * HID + tx * 8]     = o0;
            *(float4*)&Y[(size_t)row * HID + tx * 8 + 4] = o1;
        }
    }
}

// ------------- gather1: H = relu(dinv[i]*(y_i + sum_j y_j) + b1), 1 wave/node
__global__ __launch_bounds__(256) void k_gather1(const float* __restrict__ Y,
                                                 const int* __restrict__ rowptr,
                                                 const int* __restrict__ eidx,
                                                 const float* __restrict__ dinv,
                                                 const float* __restrict__ b1,
                                                 float* __restrict__ Hout) {
    int wave = (blockIdx.x * blockDim.x + threadIdx.x) >> 6;
    int lane = threadIdx.x & 63;
    if (wave >= N_NODES) return;
    const float2* yp = (const float2*)Y;
    float2 acc = yp[(size_t)wave * 64 + lane];  // self-loop (y already * dinv[src])
    int beg = rowptr[wave], end = rowptr[wave + 1];
    for (int e = beg; e < end; e++) {
        int j = eidx[e];
        float2 v = yp[(size_t)j * 64 + lane];
        acc.x += v.x; acc.y += v.y;
    }
    float s = dinv[wave];
    float2 b = ((const float2*)b1)[lane];
    float ox = fmaxf(acc.x * s + b.x, 0.f);
    float oy = fmaxf(acc.y * s + b.y, 0.f);
    ((float2*)Hout)[(size_t)wave * 64 + lane] = make_float2(ox, oy);
}

// ------------- GEMM2: Y2 = (H @ W2) * dinv[row]   (N x 128 @ 128 x 47, pad 48)
__global__ __launch_bounds__(256) void k_gemm2(const float* __restrict__ Hin,
                                               const float* __restrict__ W2,
                                               const float* __restrict__ dinv,
                                               float* __restrict__ Y2) {
    __shared__ __align__(16) float ws[128][48];
    int tid = threadIdx.x;
    for (int idx = tid; idx < 128 * 48; idx += 256) {
        int k = idx / 48, c = idx - k * 48;
        ws[k][c] = (c < NCLS) ? W2[k * NCLS + c] : 0.f;
    }
    __syncthreads();
    int row = blockIdx.x * 256 + tid;
    if (row >= N_NODES) return;
    float4 acc[12];
#pragma unroll
    for (int i = 0; i < 12; i++) acc[i] = make_float4(0.f, 0.f, 0.f, 0.f);
    const float4* h4 = (const float4*)&Hin[(size_t)row * HID];
    for (int k4 = 0; k4 < 32; k4++) {
        float4 hv = h4[k4];
#pragma unroll
        for (int u = 0; u < 4; u++) {
            float xv = (u == 0) ? hv.x : (u == 1) ? hv.y : (u == 2) ? hv.z : hv.w;
            int k = k4 * 4 + u;
#pragma unroll
            for (int c = 0; c < 12; c++) {
                float4 w = *(const float4*)&ws[k][c * 4];
                acc[c].x += xv * w.x; acc[c].y += xv * w.y;
                acc[c].z += xv * w.z; acc[c].w += xv * w.w;
            }
        }
    }
    float s = dinv[row];
#pragma unroll
    for (int c = 0; c < 12; c++) {
        float4 o = make_float4(acc[c].x * s, acc[c].y * s, acc[c].z * s, acc[c].w * s);
        *(float4*)&Y2[(size_t)row * 48 + c * 4] = o;
    }
}

// ------------- gather2: Out = dinv[i]*(y2_i + sum_j y2_j) + b2, 1 wave/node --
__global__ __launch_bounds__(256) void k_gather2(const float* __restrict__ Y2,
                                                 const int* __restrict__ rowptr,
                                                 const int* __restrict__ eidx,
                                                 const float* __restrict__ dinv,
                                                 const float* __restrict__ b2,
                                                 float* __restrict__ Out) {
    int wave = (blockIdx.x * blockDim.x + threadIdx.x) >> 6;
    int lane = threadIdx.x & 63;
    if (wave >= N_NODES) return;
    float acc = 0.f;
    if (lane < NCLS) acc = Y2[(size_t)wave * 48 + lane];
    int beg = rowptr[wave], end = rowptr[wave + 1];
    for (int e = beg; e < end; e++) {
        int j = eidx[e];
        if (lane < NCLS) acc += Y2[(size_t)j * 48 + lane];
    }
    if (lane < NCLS) Out[(size_t)wave * NCLS + lane] = acc * dinv[wave] + b2[lane];
}

// ------------- log_softmax rows of 47, in place ------------------------------
__global__ __launch_bounds__(256) void k_logsoftmax(float* __restrict__ Out) {
    int wave = (blockIdx.x * blockDim.x + threadIdx.x) >> 6;
    int lane = threadIdx.x & 63;
    if (wave >= N_NODES) return;
    float v = (lane < NCLS) ? Out[(size_t)wave * NCLS + lane] : -INFINITY;
    float m = v;
#pragma unroll
    for (int off = 32; off >= 1; off >>= 1) m = fmaxf(m, __shfl_xor(m, off, 64));
    float ex = (lane < NCLS) ? __expf(v - m) : 0.f;
    float ssum = ex;
#pragma unroll
    for (int off = 32; off >= 1; off >>= 1) ssum += __shfl_xor(ssum, off, 64);
    float l = __logf(ssum);
    if (lane < NCLS) Out[(size_t)wave * NCLS + lane] = v - m - l;
}

extern "C" void kernel_launch(void* const* d_in, const int* in_sizes, int n_in,
                              void* d_out, int out_size, void* d_ws, size_t ws_size,
                              hipStream_t stream) {
    const float* x   = (const float*)d_in[0];
    const int*   ei  = (const int*)d_in[1];
    const float* W1  = (const float*)d_in[2];
    const float* b1  = (const float*)d_in[3];
    const float* W2  = (const float*)d_in[4];
    const float* b2  = (const float*)d_in[5];
    float* out = (float*)d_out;

    const int* src = ei;             // edge_index[0]
    const int* dst = ei + N_EDGES;   // edge_index[1]

    char* ws = (char*)d_ws;
    float* y      = (float*)(ws + 0);                         // N*128 f32  (51.2 MB)
    float* h      = (float*)(ws + 51200000);                  // N*128 f32  (51.2 MB)
    float* y2     = (float*)(ws + 102400000);                 // N*48  f32  (19.2 MB)
    float* dinv   = (float*)(ws + 121600000);                 // N f32
    int*   cnt    = (int*)  (ws + 122000000);                 // N int
    int*   cursor = (int*)  (ws + 122400000);                 // N int
    int*   rowptr = (int*)  (ws + 122800000);                 // N+1 int
    int*   eidx   = (int*)  (ws + 123200016);                 // E int (6.4 MB)
    int*   bsum   = (int*)  (ws + 129600032);                 // 98 int
    int*   boff   = (int*)  (ws + 129601056);                 // 98 int

    // CSR build
    k_init<<<(N_NODES + 255) / 256, 256, 0, stream>>>(cnt, cursor);
    k_count<<<(N_EDGES + 255) / 256, 256, 0, stream>>>(dst, cnt);
    k_scan_part<<<N_SBLOCKS, 256, 0, stream>>>(cnt, bsum);
    k_scan_top<<<1, 128, 0, stream>>>(bsum, boff);
    k_scan_final<<<N_SBLOCKS, 256, 0, stream>>>(cnt, boff, rowptr, dinv);
    k_scatter<<<(N_EDGES + 255) / 256, 256, 0, stream>>>(src, dst, rowptr, cursor, eidx);

    // layer 1
    k_gemm1<<<(N_NODES + 63) / 64, 256, 0, stream>>>(x, W1, dinv, y);
    k_gather1<<<(N_NODES * 64 + 255) / 256, 256, 0, stream>>>(y, rowptr, eidx, dinv, b1, h);

    // layer 2
    k_gemm2<<<(N_NODES + 255) / 256, 256, 0, stream>>>(h, W2, dinv, y2);
    k_gather2<<<(N_NODES * 64 + 255) / 256, 256, 0, stream>>>(y2, rowptr, eidx, dinv, b2, out);

    // log_softmax
    k_logsoftmax<<<(N_NODES * 64 + 255) / 256, 256, 0, stream>>>(out);
}

// Round 4
// 515.475 us; speedup vs baseline: 1.6365x; 1.2624x over previous
//
#include <hip/hip_runtime.h>
#include <math.h>

#define N_NODES 100000
#define N_EDGES 1600000
#define F_INN   256
#define HID     128
#define NCLS    47

#define SCAN_CHUNK 1024
#define N_SBLOCKS ((N_NODES + SCAN_CHUNK - 1) / SCAN_CHUNK)  // 98

// ---------------- bf16 helpers (RNE) ----------------
__device__ __forceinline__ unsigned bf16pack(float a, float b) {
    unsigned ua = __float_as_uint(a), ub = __float_as_uint(b);
    ua = (ua + 0x7FFFu + ((ua >> 16) & 1u)) >> 16;
    ub = (ub + 0x7FFFu + ((ub >> 16) & 1u)) >> 16;
    return ua | (ub << 16);
}
__device__ __forceinline__ float2 bf16unpack(unsigned v) {
    return make_float2(__uint_as_float(v << 16), __uint_as_float(v & 0xFFFF0000u));
}
__device__ __forceinline__ float bf16tof(unsigned short u) {
    return __uint_as_float(((unsigned)u) << 16);
}

// ---------------- CSR build ----------------
__global__ void k_init(int* cnt, int* cursor) {
    int i = blockIdx.x * blockDim.x + threadIdx.x;
    if (i < N_NODES) { cnt[i] = 0; cursor[i] = 0; }
}

__global__ void k_count(const int* __restrict__ dst, int* cnt) {
    int e = blockIdx.x * blockDim.x + threadIdx.x;
    if (e < N_EDGES) atomicAdd(&cnt[dst[e]], 1);
}

// level-1: per-block (1024 counts) partial sums
__global__ __launch_bounds__(256) void k_scan_part(const int* __restrict__ cnt,
                                                   int* __restrict__ bsum) {
    int b = blockIdx.x, t = threadIdx.x;
    int base = b * SCAN_CHUNK;
    int local = 0;
#pragma unroll
    for (int u = 0; u < 4; u++) {
        int idx = base + u * 256 + t;
        if (idx < N_NODES) local += cnt[idx];
    }
#pragma unroll
    for (int off = 32; off >= 1; off >>= 1) local += __shfl_down(local, off, 64);
    __shared__ int red[4];
    if ((t & 63) == 0) red[t >> 6] = local;
    __syncthreads();
    if (t == 0) bsum[b] = red[0] + red[1] + red[2] + red[3];
}

// level-2: scan the 98 block sums (one small block)
__global__ void k_scan_top(const int* __restrict__ bsum, int* __restrict__ boff) {
    __shared__ int s[128];
    int t = threadIdx.x;
    int v = (t < N_SBLOCKS) ? bsum[t] : 0;
    s[t] = v;
    __syncthreads();
    for (int off = 1; off < 128; off <<= 1) {
        int u = (t >= off) ? s[t - off] : 0;
        __syncthreads();
        s[t] += u;
        __syncthreads();
    }
    if (t < N_SBLOCKS) boff[t] = s[t] - v;  // exclusive
}

// level-3: local scan per block + global offset -> rowptr, dinv
__global__ __launch_bounds__(256) void k_scan_final(const int* __restrict__ cnt,
                                                    const int* __restrict__ boff,
                                                    int* __restrict__ rowptr,
                                                    float* __restrict__ dinv) {
    __shared__ int tsum[256];
    int b = blockIdx.x, t = threadIdx.x;
    int base = b * SCAN_CHUNK + t * 4;
    int c[4];
    int local = 0;
#pragma unroll
    for (int u = 0; u < 4; u++) {
        int idx = base + u;
        c[u] = (idx < N_NODES) ? cnt[idx] : 0;
        local += c[u];
    }
    tsum[t] = local;
    __syncthreads();
    for (int off = 1; off < 256; off <<= 1) {
        int u = (t >= off) ? tsum[t - off] : 0;
        __syncthreads();
        tsum[t] += u;
        __syncthreads();
    }
    int run = boff[b] + tsum[t] - local;
#pragma unroll
    for (int u = 0; u < 4; u++) {
        int idx = base + u;
        if (idx < N_NODES) {
            rowptr[idx] = run;
            dinv[idx] = rsqrtf((float)c[u] + 1.0f);  // +1 self-loop
            run += c[u];
        }
    }
    if (b == 0 && t == 0) rowptr[N_NODES] = N_EDGES;
}

__global__ void k_scatter(const int* __restrict__ src, const int* __restrict__ dst,
                          const int* __restrict__ rowptr, int* cursor,
                          int* __restrict__ eidx) {
    int e = blockIdx.x * blockDim.x + threadIdx.x;
    if (e < N_EDGES) {
        int d = dst[e];
        int pos = rowptr[d] + atomicAdd(&cursor[d], 1);
        eidx[pos] = src[e];
    }
}

// ---------------- GEMM1: Yb = bf16((X @ W1) * dinv[row]) --------------------
__global__ __launch_bounds__(256) void k_gemm1(const float* __restrict__ X,
                                               const float* __restrict__ W,
                                               const float* __restrict__ dinv,
                                               unsigned* __restrict__ Yb) {
    __shared__ __align__(16) float xs[64][17];
    __shared__ __align__(16) float ws[16][128];
    int tid = threadIdx.x;
    int tx = tid & 15, ty = tid >> 4;
    int row0 = blockIdx.x * 64;

    float acc[4][8];
#pragma unroll
    for (int i = 0; i < 4; i++)
#pragma unroll
        for (int j = 0; j < 8; j++) acc[i][j] = 0.f;

    for (int k0 = 0; k0 < F_INN; k0 += 16) {
        {  // stage X tile 64x16
            int r = tid >> 2, c4 = tid & 3;
            int rr = min(row0 + r, N_NODES - 1);
            float4 v = *(const float4*)&X[(size_t)rr * F_INN + k0 + c4 * 4];
            xs[r][c4 * 4 + 0] = v.x; xs[r][c4 * 4 + 1] = v.y;
            xs[r][c4 * 4 + 2] = v.z; xs[r][c4 * 4 + 3] = v.w;
        }
#pragma unroll
        for (int t = 0; t < 2; t++) {  // stage W tile 16x128
            int idx = t * 256 + tid;   // float4 index
            int k = idx >> 5, c4 = idx & 31;
            *(float4*)&ws[k][c4 * 4] = *(const float4*)&W[(size_t)(k0 + k) * HID + c4 * 4];
        }
        __syncthreads();
#pragma unroll
        for (int kk = 0; kk < 16; kk++) {
            float xv[4];
#pragma unroll
            for (int i = 0; i < 4; i++) xv[i] = xs[ty * 4 + i][kk];
            float4 w0 = *(const float4*)&ws[kk][tx * 8];
            float4 w1 = *(const float4*)&ws[kk][tx * 8 + 4];
#pragma unroll
            for (int i = 0; i < 4; i++) {
                acc[i][0] += xv[i] * w0.x; acc[i][1] += xv[i] * w0.y;
                acc[i][2] += xv[i] * w0.z; acc[i][3] += xv[i] * w0.w;
                acc[i][4] += xv[i] * w1.x; acc[i][5] += xv[i] * w1.y;
                acc[i][6] += xv[i] * w1.z; acc[i][7] += xv[i] * w1.w;
            }
        }
        __syncthreads();
    }
#pragma unroll
    for (int i = 0; i < 4; i++) {
        int row = row0 + ty * 4 + i;
        if (row < N_NODES) {
            float s = dinv[row];
            uint4 o;
            o.x = bf16pack(acc[i][0] * s, acc[i][1] * s);
            o.y = bf16pack(acc[i][2] * s, acc[i][3] * s);
            o.z = bf16pack(acc[i][4] * s, acc[i][5] * s);
            o.w = bf16pack(acc[i][6] * s, acc[i][7] * s);
            *(uint4*)&Yb[(size_t)row * 64 + tx * 4] = o;
        }
    }
}

// ------------- gather1: H = relu(dinv[i]*(y_i + sum_j y_j) + b1), 1 wave/node
__global__ __launch_bounds__(256) void k_gather1(const unsigned* __restrict__ Yb,
                                                 const int* __restrict__ rowptr,
                                                 const int* __restrict__ eidx,
                                                 const float* __restrict__ dinv,
                                                 const float* __restrict__ b1,
                                                 float* __restrict__ Hout) {
    int wave = (blockIdx.x * blockDim.x + threadIdx.x) >> 6;
    int lane = threadIdx.x & 63;
    if (wave >= N_NODES) return;
    float2 acc = bf16unpack(Yb[(size_t)wave * 64 + lane]);  // self-loop
    int beg = rowptr[wave], end = rowptr[wave + 1];
    int e = beg;
    for (; e + 1 < end; e += 2) {
        int j0 = eidx[e], j1 = eidx[e + 1];
        unsigned v0 = Yb[(size_t)j0 * 64 + lane];
        unsigned v1 = Yb[(size_t)j1 * 64 + lane];
        float2 a = bf16unpack(v0), b = bf16unpack(v1);
        acc.x += a.x + b.x;
        acc.y += a.y + b.y;
    }
    if (e < end) {
        float2 a = bf16unpack(Yb[(size_t)eidx[e] * 64 + lane]);
        acc.x += a.x; acc.y += a.y;
    }
    float s = dinv[wave];
    float2 b = ((const float2*)b1)[lane];
    float ox = fmaxf(acc.x * s + b.x, 0.f);
    float oy = fmaxf(acc.y * s + b.y, 0.f);
    ((float2*)Hout)[(size_t)wave * 64 + lane] = make_float2(ox, oy);
}

// ------------- GEMM2: Y2b = bf16((H @ W2) * dinv[row])  (N x 128 @ 128 x 47)
__global__ __launch_bounds__(256) void k_gemm2(const float* __restrict__ Hin,
                                               const float* __restrict__ W2,
                                               const float* __restrict__ dinv,
                                               unsigned short* __restrict__ Y2b) {
    __shared__ __align__(16) float ws[128][48];
    int tid = threadIdx.x;
    for (int idx = tid; idx < 128 * 48; idx += 256) {
        int k = idx / 48, c = idx - k * 48;
        ws[k][c] = (c < NCLS) ? W2[k * NCLS + c] : 0.f;
    }
    __syncthreads();
    int row = blockIdx.x * 256 + tid;
    if (row >= N_NODES) return;
    float4 acc[12];
#pragma unroll
    for (int i = 0; i < 12; i++) acc[i] = make_float4(0.f, 0.f, 0.f, 0.f);
    const float4* h4 = (const float4*)&Hin[(size_t)row * HID];
    for (int k4 = 0; k4 < 32; k4++) {
        float4 hv = h4[k4];
#pragma unroll
        for (int u = 0; u < 4; u++) {
            float xv = (u == 0) ? hv.x : (u == 1) ? hv.y : (u == 2) ? hv.z : hv.w;
            int k = k4 * 4 + u;
#pragma unroll
            for (int c = 0; c < 12; c++) {
                float4 w = *(const float4*)&ws[k][c * 4];
                acc[c].x += xv * w.x; acc[c].y += xv * w.y;
                acc[c].z += xv * w.z; acc[c].w += xv * w.w;
            }
        }
    }
    float s = dinv[row];
#pragma unroll
    for (int c = 0; c < 12; c++) {
        uint2 o;
        o.x = bf16pack(acc[c].x * s, acc[c].y * s);
        o.y = bf16pack(acc[c].z * s, acc[c].w * s);
        *(uint2*)((char*)Y2b + ((size_t)row * 48 + c * 4) * 2) = o;
    }
}

// --- gather2 + fused log_softmax: Out = logsoftmax(dinv*(y2_i+sum y2_j)+b2) --
__global__ __launch_bounds__(256) void k_gather2(const unsigned short* __restrict__ Y2b,
                                                 const int* __restrict__ rowptr,
                                                 const int* __restrict__ eidx,
                                                 const float* __restrict__ dinv,
                                                 const float* __restrict__ b2,
                                                 float* __restrict__ Out) {
    int wave = (blockIdx.x * blockDim.x + threadIdx.x) >> 6;
    int lane = threadIdx.x & 63;
    if (wave >= N_NODES) return;
    bool act = lane < NCLS;
    float acc = 0.f;
    if (act) acc = bf16tof(Y2b[(size_t)wave * 48 + lane]);
    int beg = rowptr[wave], end = rowptr[wave + 1];
    int e = beg;
    for (; e + 1 < end; e += 2) {
        int j0 = eidx[e], j1 = eidx[e + 1];
        float v0 = 0.f, v1 = 0.f;
        if (act) {
            v0 = bf16tof(Y2b[(size_t)j0 * 48 + lane]);
            v1 = bf16tof(Y2b[(size_t)j1 * 48 + lane]);
        }
        acc += v0 + v1;
    }
    if (e < end) {
        if (act) acc += bf16tof(Y2b[(size_t)eidx[e] * 48 + lane]);
    }
    float v = act ? (acc * dinv[wave] + b2[lane]) : -INFINITY;
    // fused log_softmax over 47 lanes
    float m = v;
#pragma unroll
    for (int off = 32; off >= 1; off >>= 1) m = fmaxf(m, __shfl_xor(m, off, 64));
    float ex = act ? __expf(v - m) : 0.f;
    float ssum = ex;
#pragma unroll
    for (int off = 32; off >= 1; off >>= 1) ssum += __shfl_xor(ssum, off, 64);
    float l = __logf(ssum);
    if (act) Out[(size_t)wave * NCLS + lane] = v - m - l;
}

extern "C" void kernel_launch(void* const* d_in, const int* in_sizes, int n_in,
                              void* d_out, int out_size, void* d_ws, size_t ws_size,
                              hipStream_t stream) {
    const float* x   = (const float*)d_in[0];
    const int*   ei  = (const int*)d_in[1];
    const float* W1  = (const float*)d_in[2];
    const float* b1  = (const float*)d_in[3];
    const float* W2  = (const float*)d_in[4];
    const float* b2  = (const float*)d_in[5];
    float* out = (float*)d_out;

    const int* src = ei;             // edge_index[0]
    const int* dst = ei + N_EDGES;   // edge_index[1]

    char* ws = (char*)d_ws;
    unsigned*       yb   = (unsigned*)      (ws + 0);          // N*64 u32  (25.6 MB)
    float*          h    = (float*)         (ws + 25600000);   // N*128 f32 (51.2 MB)
    unsigned short* y2b  = (unsigned short*)(ws + 76800000);   // N*48 u16  (9.6 MB)
    float*          dinv = (float*)         (ws + 86400000);   // N f32
    int*            cnt  = (int*)           (ws + 86800000);   // N int
    int*            cursor=(int*)           (ws + 87200000);   // N int
    int*            rowptr=(int*)           (ws + 87600000);   // N+1 int
    int*            eidx = (int*)           (ws + 88000016);   // E int (6.4 MB)
    int*            bsum = (int*)           (ws + 94400016);   // 98 int
    int*            boff = (int*)           (ws + 94400416);   // 98 int

    // CSR build
    k_init<<<(N_NODES + 255) / 256, 256, 0, stream>>>(cnt, cursor);
    k_count<<<(N_EDGES + 255) / 256, 256, 0, stream>>>(dst, cnt);
    k_scan_part<<<N_SBLOCKS, 256, 0, stream>>>(cnt, bsum);
    k_scan_top<<<1, 128, 0, stream>>>(bsum, boff);
    k_scan_final<<<N_SBLOCKS, 256, 0, stream>>>(cnt, boff, rowptr, dinv);
    k_scatter<<<(N_EDGES + 255) / 256, 256, 0, stream>>>(src, dst, rowptr, cursor, eidx);

    // layer 1
    k_gemm1<<<(N_NODES + 63) / 64, 256, 0, stream>>>(x, W1, dinv, yb);
    k_gather1<<<(N_NODES * 64 + 255) / 256, 256, 0, stream>>>(yb, rowptr, eidx, dinv, b1, h);

    // layer 2
    k_gemm2<<<(N_NODES + 255) / 256, 256, 0, stream>>>(h, W2, dinv, y2b);
    k_gather2<<<(N_NODES * 64 + 255) / 256, 256, 0, stream>>>(y2b, rowptr, eidx, dinv, b2, out);
}

// Round 5
// 430.065 us; speedup vs baseline: 1.9615x; 1.1986x over previous
//
#include <hip/hip_runtime.h>
#include <math.h>

#define N_NODES 100000
#define N_EDGES 1600000
#define F_INN   256
#define HID     128
#define NCLS    47

#define SCAN_CHUNK 1024
#define N_SBLOCKS ((N_NODES + SCAN_CHUNK - 1) / SCAN_CHUNK)  // 98

// ---------------- bf16 helpers (RNE) ----------------
__device__ __forceinline__ unsigned bf16pack(float a, float b) {
    unsigned ua = __float_as_uint(a), ub = __float_as_uint(b);
    ua = (ua + 0x7FFFu + ((ua >> 16) & 1u)) >> 16;
    ub = (ub + 0x7FFFu + ((ub >> 16) & 1u)) >> 16;
    return ua | (ub << 16);
}
__device__ __forceinline__ float2 bf16unpack(unsigned v) {
    return make_float2(__uint_as_float(v << 16), __uint_as_float(v & 0xFFFF0000u));
}
__device__ __forceinline__ float bf16tof(unsigned short u) {
    return __uint_as_float(((unsigned)u) << 16);
}

// ---------------- CSR build ----------------
__global__ void k_init(int* cnt) {
    int i = blockIdx.x * blockDim.x + threadIdx.x;
    if (i < N_NODES) cnt[i] = 0;
}

// count + record within-node rank (the atomic's return value)
__global__ void k_count(const int* __restrict__ dst, int* cnt,
                        unsigned char* __restrict__ rank) {
    int e = blockIdx.x * blockDim.x + threadIdx.x;
    if (e < N_EDGES) rank[e] = (unsigned char)atomicAdd(&cnt[dst[e]], 1);
}

// level-1: per-block (1024 counts) partial sums
__global__ __launch_bounds__(256) void k_scan_part(const int* __restrict__ cnt,
                                                   int* __restrict__ bsum) {
    int b = blockIdx.x, t = threadIdx.x;
    int base = b * SCAN_CHUNK;
    int local = 0;
#pragma unroll
    for (int u = 0; u < 4; u++) {
        int idx = base + u * 256 + t;
        if (idx < N_NODES) local += cnt[idx];
    }
#pragma unroll
    for (int off = 32; off >= 1; off >>= 1) local += __shfl_down(local, off, 64);
    __shared__ int red[4];
    if ((t & 63) == 0) red[t >> 6] = local;
    __syncthreads();
    if (t == 0) bsum[b] = red[0] + red[1] + red[2] + red[3];
}

// level-2: scan the 98 block sums (one small block)
__global__ void k_scan_top(const int* __restrict__ bsum, int* __restrict__ boff) {
    __shared__ int s[128];
    int t = threadIdx.x;
    int v = (t < N_SBLOCKS) ? bsum[t] : 0;
    s[t] = v;
    __syncthreads();
    for (int off = 1; off < 128; off <<= 1) {
        int u = (t >= off) ? s[t - off] : 0;
        __syncthreads();
        s[t] += u;
        __syncthreads();
    }
    if (t < N_SBLOCKS) boff[t] = s[t] - v;  // exclusive
}

// level-3: local scan per block + global offset -> rowptr, dinv
__global__ __launch_bounds__(256) void k_scan_final(const int* __restrict__ cnt,
                                                    const int* __restrict__ boff,
                                                    int* __restrict__ rowptr,
                                                    float* __restrict__ dinv) {
    __shared__ int tsum[256];
    int b = blockIdx.x, t = threadIdx.x;
    int base = b * SCAN_CHUNK + t * 4;
    int c[4];
    int local = 0;
#pragma unroll
    for (int u = 0; u < 4; u++) {
        int idx = base + u;
        c[u] = (idx < N_NODES) ? cnt[idx] : 0;
        local += c[u];
    }
    tsum[t] = local;
    __syncthreads();
    for (int off = 1; off < 256; off <<= 1) {
        int u = (t >= off) ? tsum[t - off] : 0;
        __syncthreads();
        tsum[t] += u;
        __syncthreads();
    }
    int run = boff[b] + tsum[t] - local;
#pragma unroll
    for (int u = 0; u < 4; u++) {
        int idx = base + u;
        if (idx < N_NODES) {
            rowptr[idx] = run;
            dinv[idx] = rsqrtf((float)c[u] + 1.0f);  // +1 self-loop
            run += c[u];
        }
    }
    if (b == 0 && t == 0) rowptr[N_NODES] = N_EDGES;
}

// atomic-free scatter using precomputed rank
__global__ void k_scatter(const int* __restrict__ src, const int* __restrict__ dst,
                          const int* __restrict__ rowptr,
                          const unsigned char* __restrict__ rank,
                          int* __restrict__ eidx) {
    int e = blockIdx.x * blockDim.x + threadIdx.x;
    if (e < N_EDGES) {
        int d = dst[e];
        eidx[rowptr[d] + (int)rank[e]] = src[e];
    }
}

// ---------------- GEMM1: Yb = bf16((X @ W1) * dinv[row]) --------------------
__global__ __launch_bounds__(256) void k_gemm1(const float* __restrict__ X,
                                               const float* __restrict__ W,
                                               const float* __restrict__ dinv,
                                               unsigned* __restrict__ Yb) {
    __shared__ __align__(16) float xs[64][17];
    __shared__ __align__(16) float ws[16][128];
    int tid = threadIdx.x;
    int tx = tid & 15, ty = tid >> 4;
    int row0 = blockIdx.x * 64;

    float acc[4][8];
#pragma unroll
    for (int i = 0; i < 4; i++)
#pragma unroll
        for (int j = 0; j < 8; j++) acc[i][j] = 0.f;

    for (int k0 = 0; k0 < F_INN; k0 += 16) {
        {  // stage X tile 64x16
            int r = tid >> 2, c4 = tid & 3;
            int rr = min(row0 + r, N_NODES - 1);
            float4 v = *(const float4*)&X[(size_t)rr * F_INN + k0 + c4 * 4];
            xs[r][c4 * 4 + 0] = v.x; xs[r][c4 * 4 + 1] = v.y;
            xs[r][c4 * 4 + 2] = v.z; xs[r][c4 * 4 + 3] = v.w;
        }
#pragma unroll
        for (int t = 0; t < 2; t++) {  // stage W tile 16x128
            int idx = t * 256 + tid;   // float4 index
            int k = idx >> 5, c4 = idx & 31;
            *(float4*)&ws[k][c4 * 4] = *(const float4*)&W[(size_t)(k0 + k) * HID + c4 * 4];
        }
        __syncthreads();
#pragma unroll
        for (int kk = 0; kk < 16; kk++) {
            float xv[4];
#pragma unroll
            for (int i = 0; i < 4; i++) xv[i] = xs[ty * 4 + i][kk];
            float4 w0 = *(const float4*)&ws[kk][tx * 8];
            float4 w1 = *(const float4*)&ws[kk][tx * 8 + 4];
#pragma unroll
            for (int i = 0; i < 4; i++) {
                acc[i][0] += xv[i] * w0.x; acc[i][1] += xv[i] * w0.y;
                acc[i][2] += xv[i] * w0.z; acc[i][3] += xv[i] * w0.w;
                acc[i][4] += xv[i] * w1.x; acc[i][5] += xv[i] * w1.y;
                acc[i][6] += xv[i] * w1.z; acc[i][7] += xv[i] * w1.w;
            }
        }
        __syncthreads();
    }
#pragma unroll
    for (int i = 0; i < 4; i++) {
        int row = row0 + ty * 4 + i;
        if (row < N_NODES) {
            float s = dinv[row];
            uint4 o;
            o.x = bf16pack(acc[i][0] * s, acc[i][1] * s);
            o.y = bf16pack(acc[i][2] * s, acc[i][3] * s);
            o.z = bf16pack(acc[i][4] * s, acc[i][5] * s);
            o.w = bf16pack(acc[i][6] * s, acc[i][7] * s);
            *(uint4*)&Yb[(size_t)row * 64 + tx * 4] = o;
        }
    }
}

// ------------- gather1: H = relu(dinv[i]*(y_i + sum_j y_j) + b1), 1 wave/node
__global__ __launch_bounds__(256) void k_gather1(const unsigned* __restrict__ Yb,
                                                 const int* __restrict__ rowptr,
                                                 const int* __restrict__ eidx,
                                                 const float* __restrict__ dinv,
                                                 const float* __restrict__ b1,
                                                 float* __restrict__ Hout) {
    int wave = (blockIdx.x * blockDim.x + threadIdx.x) >> 6;
    int lane = threadIdx.x & 63;
    if (wave >= N_NODES) return;
    float2 acc = bf16unpack(Yb[(size_t)wave * 64 + lane]);  // self-loop
    int beg = rowptr[wave], end = rowptr[wave + 1];
    int e = beg;
    for (; e + 3 < end; e += 4) {
        int j0 = eidx[e], j1 = eidx[e + 1], j2 = eidx[e + 2], j3 = eidx[e + 3];
        unsigned v0 = Yb[(size_t)j0 * 64 + lane];
        unsigned v1 = Yb[(size_t)j1 * 64 + lane];
        unsigned v2 = Yb[(size_t)j2 * 64 + lane];
        unsigned v3 = Yb[(size_t)j3 * 64 + lane];
        float2 a = bf16unpack(v0), b = bf16unpack(v1);
        float2 c = bf16unpack(v2), d = bf16unpack(v3);
        acc.x += (a.x + b.x) + (c.x + d.x);
        acc.y += (a.y + b.y) + (c.y + d.y);
    }
    for (; e < end; e++) {
        float2 a = bf16unpack(Yb[(size_t)eidx[e] * 64 + lane]);
        acc.x += a.x; acc.y += a.y;
    }
    float s = dinv[wave];
    float2 b = ((const float2*)b1)[lane];
    float ox = fmaxf(acc.x * s + b.x, 0.f);
    float oy = fmaxf(acc.y * s + b.y, 0.f);
    ((float2*)Hout)[(size_t)wave * 64 + lane] = make_float2(ox, oy);
}

// ------------- GEMM2: Y2b = bf16((H @ W2) * dinv[row])  (N x 128 @ 128 x 47)
__global__ __launch_bounds__(256) void k_gemm2(const float* __restrict__ Hin,
                                               const float* __restrict__ W2,
                                               const float* __restrict__ dinv,
                                               unsigned short* __restrict__ Y2b) {
    __shared__ __align__(16) float ws[128][48];
    int tid = threadIdx.x;
    for (int idx = tid; idx < 128 * 48; idx += 256) {
        int k = idx / 48, c = idx - k * 48;
        ws[k][c] = (c < NCLS) ? W2[k * NCLS + c] : 0.f;
    }
    __syncthreads();
    int row = blockIdx.x * 256 + tid;
    if (row >= N_NODES) return;
    float4 acc[12];
#pragma unroll
    for (int i = 0; i < 12; i++) acc[i] = make_float4(0.f, 0.f, 0.f, 0.f);
    const float4* h4 = (const float4*)&Hin[(size_t)row * HID];
    for (int k4 = 0; k4 < 32; k4++) {
        float4 hv = h4[k4];
#pragma unroll
        for (int u = 0; u < 4; u++) {
            float xv = (u == 0) ? hv.x : (u == 1) ? hv.y : (u == 2) ? hv.z : hv.w;
            int k = k4 * 4 + u;
#pragma unroll
            for (int c = 0; c < 12; c++) {
                float4 w = *(const float4*)&ws[k][c * 4];
                acc[c].x += xv * w.x; acc[c].y += xv * w.y;
                acc[c].z += xv * w.z; acc[c].w += xv * w.w;
            }
        }
    }
    float s = dinv[row];
#pragma unroll
    for (int c = 0; c < 12; c++) {
        uint2 o;
        o.x = bf16pack(acc[c].x * s, acc[c].y * s);
        o.y = bf16pack(acc[c].z * s, acc[c].w * s);
        *(uint2*)((char*)Y2b + ((size_t)row * 48 + c * 4) * 2) = o;
    }
}

// --- gather2 + fused log_softmax: Out = logsoftmax(dinv*(y2_i+sum y2_j)+b2) --
__global__ __launch_bounds__(256) void k_gather2(const unsigned short* __restrict__ Y2b,
                                                 const int* __restrict__ rowptr,
                                                 const int* __restrict__ eidx,
                                                 const float* __restrict__ dinv,
                                                 const float* __restrict__ b2,
                                                 float* __restrict__ Out) {
    int wave = (blockIdx.x * blockDim.x + threadIdx.x) >> 6;
    int lane = threadIdx.x & 63;
    if (wave >= N_NODES) return;
    bool act = lane < NCLS;
    float acc = 0.f;
    if (act) acc = bf16tof(Y2b[(size_t)wave * 48 + lane]);
    int beg = rowptr[wave], end = rowptr[wave + 1];
    int e = beg;
    for (; e + 1 < end; e += 2) {
        int j0 = eidx[e], j1 = eidx[e + 1];
        float v0 = 0.f, v1 = 0.f;
        if (act) {
            v0 = bf16tof(Y2b[(size_t)j0 * 48 + lane]);
            v1 = bf16tof(Y2b[(size_t)j1 * 48 + lane]);
        }
        acc += v0 + v1;
    }
    if (e < end) {
        if (act) acc += bf16tof(Y2b[(size_t)eidx[e] * 48 + lane]);
    }
    float v = act ? (acc * dinv[wave] + b2[lane]) : -INFINITY;
    // fused log_softmax over 47 lanes
    float m = v;
#pragma unroll
    for (int off = 32; off >= 1; off >>= 1) m = fmaxf(m, __shfl_xor(m, off, 64));
    float ex = act ? __expf(v - m) : 0.f;
    float ssum = ex;
#pragma unroll
    for (int off = 32; off >= 1; off >>= 1) ssum += __shfl_xor(ssum, off, 64);
    float l = __logf(ssum);
    if (act) Out[(size_t)wave * NCLS + lane] = v - m - l;
}

extern "C" void kernel_launch(void* const* d_in, const int* in_sizes, int n_in,
                              void* d_out, int out_size, void* d_ws, size_t ws_size,
                              hipStream_t stream) {
    const float* x   = (const float*)d_in[0];
    const int*   ei  = (const int*)d_in[1];
    const float* W1  = (const float*)d_in[2];
    const float* b1  = (const float*)d_in[3];
    const float* W2  = (const float*)d_in[4];
    const float* b2  = (const float*)d_in[5];
    float* out = (float*)d_out;

    const int* src = ei;             // edge_index[0]
    const int* dst = ei + N_EDGES;   // edge_index[1]

    char* ws = (char*)d_ws;
    unsigned*       yb   = (unsigned*)      (ws + 0);          // N*64 u32  (25.6 MB)
    float*          h    = (float*)         (ws + 25600000);   // N*128 f32 (51.2 MB)
    unsigned short* y2b  = (unsigned short*)(ws + 76800000);   // N*48 u16  (9.6 MB)
    float*          dinv = (float*)         (ws + 86400000);   // N f32
    int*            cnt  = (int*)           (ws + 86800000);   // N int
    int*            rowptr=(int*)           (ws + 87600000);   // N+1 int
    int*            eidx = (int*)           (ws + 88000016);   // E int (6.4 MB)
    int*            bsum = (int*)           (ws + 94400016);   // 98 int
    int*            boff = (int*)           (ws + 94400416);   // 98 int
    unsigned char*  rank = (unsigned char*) (ws + 94401440);   // E u8 (1.6 MB)

    // CSR build
    k_init<<<(N_NODES + 255) / 256, 256, 0, stream>>>(cnt);
    k_count<<<(N_EDGES + 255) / 256, 256, 0, stream>>>(dst, cnt, rank);
    k_scan_part<<<N_SBLOCKS, 256, 0, stream>>>(cnt, bsum);
    k_scan_top<<<1, 128, 0, stream>>>(bsum, boff);
    k_scan_final<<<N_SBLOCKS, 256, 0, stream>>>(cnt, boff, rowptr, dinv);
    k_scatter<<<(N_EDGES + 255) / 256, 256, 0, stream>>>(src, dst, rowptr, rank, eidx);

    // layer 1
    k_gemm1<<<(N_NODES + 63) / 64, 256, 0, stream>>>(x, W1, dinv, yb);
    k_gather1<<<(N_NODES * 64 + 255) / 256, 256, 0, stream>>>(yb, rowptr, eidx, dinv, b1, h);

    // layer 2
    k_gemm2<<<(N_NODES + 255) / 256, 256, 0, stream>>>(h, W2, dinv, y2b);
    k_gather2<<<(N_NODES * 64 + 255) / 256, 256, 0, stream>>>(y2b, rowptr, eidx, dinv, b2, out);
}

// Round 6
// 358.716 us; speedup vs baseline: 2.3516x; 1.1989x over previous
//
#include <hip/hip_runtime.h>
#include <math.h>

#define N_NODES 100000
#define N_EDGES 1600000
#define F_INN   256
#define HID     128
#define NCLS    47

#define SCAN_CHUNK 1024
#define N_SBLOCKS ((N_NODES + SCAN_CHUNK - 1) / SCAN_CHUNK)  // 98

typedef __attribute__((ext_vector_type(8))) short bf16x8;
typedef __attribute__((ext_vector_type(4))) float f32x4;

// ---------------- bf16 helpers (RNE) ----------------
__device__ __forceinline__ unsigned bf16pack(float a, float b) {
    unsigned ua = __float_as_uint(a), ub = __float_as_uint(b);
    ua = (ua + 0x7FFFu + ((ua >> 16) & 1u)) >> 16;
    ub = (ub + 0x7FFFu + ((ub >> 16) & 1u)) >> 16;
    return ua | (ub << 16);
}
__device__ __forceinline__ float2 bf16unpack(unsigned v) {
    return make_float2(__uint_as_float(v << 16), __uint_as_float(v & 0xFFFF0000u));
}
__device__ __forceinline__ float bf16tof(unsigned short u) {
    return __uint_as_float(((unsigned)u) << 16);
}

// ---------------- CSR build ----------------
__global__ void k_init(int* cnt) {
    int i = blockIdx.x * blockDim.x + threadIdx.x;
    if (i < N_NODES) cnt[i] = 0;
}

// count + record within-node rank (the atomic's return value)
__global__ void k_count(const int* __restrict__ dst, int* cnt,
                        unsigned char* __restrict__ rank) {
    int e = blockIdx.x * blockDim.x + threadIdx.x;
    if (e < N_EDGES) rank[e] = (unsigned char)atomicAdd(&cnt[dst[e]], 1);
}

// level-1: per-block (1024 counts) partial sums
__global__ __launch_bounds__(256) void k_scan_part(const int* __restrict__ cnt,
                                                   int* __restrict__ bsum) {
    int b = blockIdx.x, t = threadIdx.x;
    int base = b * SCAN_CHUNK;
    int local = 0;
#pragma unroll
    for (int u = 0; u < 4; u++) {
        int idx = base + u * 256 + t;
        if (idx < N_NODES) local += cnt[idx];
    }
#pragma unroll
    for (int off = 32; off >= 1; off >>= 1) local += __shfl_down(local, off, 64);
    __shared__ int red[4];
    if ((t & 63) == 0) red[t >> 6] = local;
    __syncthreads();
    if (t == 0) bsum[b] = red[0] + red[1] + red[2] + red[3];
}

// level-2: scan the 98 block sums (one small block)
__global__ void k_scan_top(const int* __restrict__ bsum, int* __restrict__ boff) {
    __shared__ int s[128];
    int t = threadIdx.x;
    int v = (t < N_SBLOCKS) ? bsum[t] : 0;
    s[t] = v;
    __syncthreads();
    for (int off = 1; off < 128; off <<= 1) {
        int u = (t >= off) ? s[t - off] : 0;
        __syncthreads();
        s[t] += u;
        __syncthreads();
    }
    if (t < N_SBLOCKS) boff[t] = s[t] - v;  // exclusive
}

// level-3: local scan per block + global offset -> rowptr, dinv
__global__ __launch_bounds__(256) void k_scan_final(const int* __restrict__ cnt,
                                                    const int* __restrict__ boff,
                                                    int* __restrict__ rowptr,
                                                    float* __restrict__ dinv) {
    __shared__ int tsum[256];
    int b = blockIdx.x, t = threadIdx.x;
    int base = b * SCAN_CHUNK + t * 4;
    int c[4];
    int local = 0;
#pragma unroll
    for (int u = 0; u < 4; u++) {
        int idx = base + u;
        c[u] = (idx < N_NODES) ? cnt[idx] : 0;
        local += c[u];
    }
    tsum[t] = local;
    __syncthreads();
    for (int off = 1; off < 256; off <<= 1) {
        int u = (t >= off) ? tsum[t - off] : 0;
        __syncthreads();
        tsum[t] += u;
        __syncthreads();
    }
    int run = boff[b] + tsum[t] - local;
#pragma unroll
    for (int u = 0; u < 4; u++) {
        int idx = base + u;
        if (idx < N_NODES) {
            rowptr[idx] = run;
            dinv[idx] = rsqrtf((float)c[u] + 1.0f);  // +1 self-loop
            run += c[u];
        }
    }
    if (b == 0 && t == 0) rowptr[N_NODES] = N_EDGES;
}

// atomic-free scatter using precomputed rank
__global__ void k_scatter(const int* __restrict__ src, const int* __restrict__ dst,
                          const int* __restrict__ rowptr,
                          const unsigned char* __restrict__ rank,
                          int* __restrict__ eidx) {
    int e = blockIdx.x * blockDim.x + threadIdx.x;
    if (e < N_EDGES) {
        int d = dst[e];
        eidx[rowptr[d] + (int)rank[e]] = src[e];
    }
}

// ---- prep: W1 (256x128 f32) -> MFMA-fragment-ordered bf16 ------------------
// Fragment g = nt*8 + kst (nt: 16-col tile, kst: 32-k step). Lane l of frag g
// holds 8 bf16: W1[kst*32 + (l>>4)*8 + j][nt*16 + (l&15)], j=0..7 (16B).
__global__ __launch_bounds__(256) void k_prep(const float* __restrict__ W1,
                                              uint4* __restrict__ Wf) {
    int g = blockIdx.x * blockDim.x + threadIdx.x;  // 0..4095
    if (g >= 4096) return;
    int l = g & 63;
    int kst = (g >> 6) & 7;
    int nt = g >> 9;
    int n = nt * 16 + (l & 15);
    int kb = kst * 32 + ((l >> 4) << 3);
    float v[8];
#pragma unroll
    for (int j = 0; j < 8; j++) v[j] = W1[(size_t)(kb + j) * HID + n];
    uint4 o;
    o.x = bf16pack(v[0], v[1]);
    o.y = bf16pack(v[2], v[3]);
    o.z = bf16pack(v[4], v[5]);
    o.w = bf16pack(v[6], v[7]);
    Wf[g] = o;
}

// ---------------- GEMM1 (MFMA): Yb = bf16((X @ W1) * dinv[row]) -------------
// 128x128 tile, 4 waves (2x2), 16x16x32 bf16 MFMA, K=256 in 8 steps.
__global__ __launch_bounds__(256) void k_gemm1(const float* __restrict__ X,
                                               const uint4* __restrict__ Wf,
                                               const float* __restrict__ dinv,
                                               unsigned* __restrict__ Yb) {
    __shared__ __align__(16) unsigned short xs[128 * 32];
    int tid = threadIdx.x;
    int lane = tid & 63, w = tid >> 6;
    int wr = w >> 1, wc = w & 1;
    int row0 = blockIdx.x * 128;

    f32x4 acc[4][4];  // [fm][fn]
#pragma unroll
    for (int i = 0; i < 4; i++)
#pragma unroll
        for (int j = 0; j < 4; j++) acc[i][j] = (f32x4){0.f, 0.f, 0.f, 0.f};

    for (int ks = 0; ks < 8; ks++) {
        int k0 = ks * 32;
        // stage X tile [128 rows][32 k] f32 -> bf16 (coalesced, conflict-free)
#pragma unroll
        for (int u = 0; u < 4; u++) {
            int slot = u * 256 + tid;          // 0..1023
            int r = slot >> 3, c4 = slot & 7;  // row, float4-slot
            int rr = min(row0 + r, N_NODES - 1);
            float4 v = *(const float4*)&X[(size_t)rr * F_INN + k0 + c4 * 4];
            uint2 p;
            p.x = bf16pack(v.x, v.y);
            p.y = bf16pack(v.z, v.w);
            *(uint2*)&xs[r * 32 + c4 * 4] = p;
        }
        // B-frags straight from global (64KB, L2-hot)
        bf16x8 bfr[4];
#pragma unroll
        for (int fn = 0; fn < 4; fn++) {
            uint4 t = Wf[((wc * 4 + fn) * 8 + ks) * 64 + lane];
            bfr[fn] = *(bf16x8*)&t;
        }
        __syncthreads();
        bf16x8 afr[4];
#pragma unroll
        for (int fm = 0; fm < 4; fm++) {
            int r = wr * 64 + fm * 16 + (lane & 15);
            afr[fm] = *(const bf16x8*)&xs[r * 32 + ((lane >> 4) << 3)];
        }
#pragma unroll
        for (int fm = 0; fm < 4; fm++)
#pragma unroll
            for (int fn = 0; fn < 4; fn++)
                acc[fm][fn] = __builtin_amdgcn_mfma_f32_16x16x32_bf16(
                    bfr[fn], afr[fm], acc[fm][fn], 0, 0, 0);
        __syncthreads();
    }
    // epilogue: regs sweep n (first operand = W), lane&15 = row within fm-tile
#pragma unroll
    for (int fm = 0; fm < 4; fm++) {
        int row = row0 + wr * 64 + fm * 16 + (lane & 15);
        if (row < N_NODES) {
            float s = dinv[row];
            unsigned short* yrow = (unsigned short*)Yb + (size_t)row * 128;
#pragma unroll
            for (int fn = 0; fn < 4; fn++) {
                int col = wc * 64 + fn * 16 + ((lane >> 4) << 2);
                uint2 p;
                p.x = bf16pack(acc[fm][fn][0] * s, acc[fm][fn][1] * s);
                p.y = bf16pack(acc[fm][fn][2] * s, acc[fm][fn][3] * s);
                *(uint2*)&yrow[col] = p;
            }
        }
    }
}

// ------------- gather1: Hb = bf16(relu(dinv[i]*(y_i + sum_j y_j) + b1)) -----
__global__ __launch_bounds__(256) void k_gather1(const unsigned* __restrict__ Yb,
                                                 const int* __restrict__ rowptr,
                                                 const int* __restrict__ eidx,
                                                 const float* __restrict__ dinv,
                                                 const float* __restrict__ b1,
                                                 unsigned* __restrict__ Hb) {
    int wave = (blockIdx.x * blockDim.x + threadIdx.x) >> 6;
    int lane = threadIdx.x & 63;
    if (wave >= N_NODES) return;
    float2 acc = bf16unpack(Yb[(size_t)wave * 64 + lane]);  // self-loop
    int beg = rowptr[wave], end = rowptr[wave + 1];
    int e = beg;
    for (; e + 3 < end; e += 4) {
        int j0 = eidx[e], j1 = eidx[e + 1], j2 = eidx[e + 2], j3 = eidx[e + 3];
        unsigned v0 = Yb[(size_t)j0 * 64 + lane];
        unsigned v1 = Yb[(size_t)j1 * 64 + lane];
        unsigned v2 = Yb[(size_t)j2 * 64 + lane];
        unsigned v3 = Yb[(size_t)j3 * 64 + lane];
        float2 a = bf16unpack(v0), b = bf16unpack(v1);
        float2 c = bf16unpack(v2), d = bf16unpack(v3);
        acc.x += (a.x + b.x) + (c.x + d.x);
        acc.y += (a.y + b.y) + (c.y + d.y);
    }
    for (; e < end; e++) {
        float2 a = bf16unpack(Yb[(size_t)eidx[e] * 64 + lane]);
        acc.x += a.x; acc.y += a.y;
    }
    float s = dinv[wave];
    float2 b = ((const float2*)b1)[lane];
    float ox = fmaxf(acc.x * s + b.x, 0.f);
    float oy = fmaxf(acc.y * s + b.y, 0.f);
    Hb[(size_t)wave * 64 + lane] = bf16pack(ox, oy);
}

// ------------- GEMM2: Y2b = bf16((H @ W2) * dinv[row])  (N x 128 @ 128 x 47)
__global__ __launch_bounds__(256) void k_gemm2(const unsigned* __restrict__ Hb,
                                               const float* __restrict__ W2,
                                               const float* __restrict__ dinv,
                                               unsigned short* __restrict__ Y2b) {
    __shared__ __align__(16) float ws[128][48];
    int tid = threadIdx.x;
    for (int idx = tid; idx < 128 * 48; idx += 256) {
        int k = idx / 48, c = idx - k * 48;
        ws[k][c] = (c < NCLS) ? W2[k * NCLS + c] : 0.f;
    }
    __syncthreads();
    int row = blockIdx.x * 256 + tid;
    if (row >= N_NODES) return;
    float4 acc[12];
#pragma unroll
    for (int i = 0; i < 12; i++) acc[i] = make_float4(0.f, 0.f, 0.f, 0.f);
    const uint4* h4 = (const uint4*)(Hb + (size_t)row * 64);
    for (int kq = 0; kq < 16; kq++) {
        uint4 hv = h4[kq];
        float f[8];
        float2 f0 = bf16unpack(hv.x), f1 = bf16unpack(hv.y);
        float2 f2 = bf16unpack(hv.z), f3 = bf16unpack(hv.w);
        f[0] = f0.x; f[1] = f0.y; f[2] = f1.x; f[3] = f1.y;
        f[4] = f2.x; f[5] = f2.y; f[6] = f3.x; f[7] = f3.y;
#pragma unroll
        for (int u = 0; u < 8; u++) {
            float xv = f[u];
            int k = kq * 8 + u;
#pragma unroll
            for (int c = 0; c < 12; c++) {
                float4 w = *(const float4*)&ws[k][c * 4];
                acc[c].x += xv * w.x; acc[c].y += xv * w.y;
                acc[c].z += xv * w.z; acc[c].w += xv * w.w;
            }
        }
    }
    float s = dinv[row];
#pragma unroll
    for (int c = 0; c < 12; c++) {
        uint2 o;
        o.x = bf16pack(acc[c].x * s, acc[c].y * s);
        o.y = bf16pack(acc[c].z * s, acc[c].w * s);
        *(uint2*)((char*)Y2b + ((size_t)row * 48 + c * 4) * 2) = o;
    }
}

// --- gather2 + fused log_softmax: Out = logsoftmax(dinv*(y2_i+sum y2_j)+b2) --
__global__ __launch_bounds__(256) void k_gather2(const unsigned short* __restrict__ Y2b,
                                                 const int* __restrict__ rowptr,
                                                 const int* __restrict__ eidx,
                                                 const float* __restrict__ dinv,
                                                 const float* __restrict__ b2,
                                                 float* __restrict__ Out) {
    int wave = (blockIdx.x * blockDim.x + threadIdx.x) >> 6;
    int lane = threadIdx.x & 63;
    if (wave >= N_NODES) return;
    bool act = lane < NCLS;
    float acc = 0.f;
    if (act) acc = bf16tof(Y2b[(size_t)wave * 48 + lane]);
    int beg = rowptr[wave], end = rowptr[wave + 1];
    int e = beg;
    for (; e + 1 < end; e += 2) {
        int j0 = eidx[e], j1 = eidx[e + 1];
        float v0 = 0.f, v1 = 0.f;
        if (act) {
            v0 = bf16tof(Y2b[(size_t)j0 * 48 + lane]);
            v1 = bf16tof(Y2b[(size_t)j1 * 48 + lane]);
        }
        acc += v0 + v1;
    }
    if (e < end) {
        if (act) acc += bf16tof(Y2b[(size_t)eidx[e] * 48 + lane]);
    }
    float v = act ? (acc * dinv[wave] + b2[lane]) : -INFINITY;
    // fused log_softmax over 47 lanes
    float m = v;
#pragma unroll
    for (int off = 32; off >= 1; off >>= 1) m = fmaxf(m, __shfl_xor(m, off, 64));
    float ex = act ? __expf(v - m) : 0.f;
    float ssum = ex;
#pragma unroll
    for (int off = 32; off >= 1; off >>= 1) ssum += __shfl_xor(ssum, off, 64);
    float l = __logf(ssum);
    if (act) Out[(size_t)wave * NCLS + lane] = v - m - l;
}

extern "C" void kernel_launch(void* const* d_in, const int* in_sizes, int n_in,
                              void* d_out, int out_size, void* d_ws, size_t ws_size,
                              hipStream_t stream) {
    const float* x   = (const float*)d_in[0];
    const int*   ei  = (const int*)d_in[1];
    const float* W1  = (const float*)d_in[2];
    const float* b1  = (const float*)d_in[3];
    const float* W2  = (const float*)d_in[4];
    const float* b2  = (const float*)d_in[5];
    float* out = (float*)d_out;

    const int* src = ei;             // edge_index[0]
    const int* dst = ei + N_EDGES;   // edge_index[1]

    char* ws = (char*)d_ws;
    unsigned*       yb   = (unsigned*)      (ws + 0);          // N*64 u32  (25.6 MB)
    unsigned*       hb   = (unsigned*)      (ws + 25600000);   // N*64 u32  (25.6 MB)
    unsigned short* y2b  = (unsigned short*)(ws + 51200000);   // N*48 u16  (9.6 MB)
    float*          dinv = (float*)         (ws + 60800000);   // N f32
    int*            cnt  = (int*)           (ws + 61200000);   // N int
    int*            rowptr=(int*)           (ws + 61600000);   // N+1 int
    int*            eidx = (int*)           (ws + 62000016);   // E int (6.4 MB)
    int*            bsum = (int*)           (ws + 68400016);   // 98 int
    int*            boff = (int*)           (ws + 68401040);   // 98 int
    unsigned char*  rank = (unsigned char*) (ws + 68402064);   // E u8 (1.6 MB)
    uint4*          wfrag= (uint4*)         (ws + 70002064);   // 64 KB

    // CSR build
    k_init<<<(N_NODES + 255) / 256, 256, 0, stream>>>(cnt);
    k_count<<<(N_EDGES + 255) / 256, 256, 0, stream>>>(dst, cnt, rank);
    k_scan_part<<<N_SBLOCKS, 256, 0, stream>>>(cnt, bsum);
    k_scan_top<<<1, 128, 0, stream>>>(bsum, boff);
    k_scan_final<<<N_SBLOCKS, 256, 0, stream>>>(cnt, boff, rowptr, dinv);
    k_scatter<<<(N_EDGES + 255) / 256, 256, 0, stream>>>(src, dst, rowptr, rank, eidx);

    // W1 -> fragment-ordered bf16
    k_prep<<<16, 256, 0, stream>>>(W1, wfrag);

    // layer 1
    k_gemm1<<<(N_NODES + 127) / 128, 256, 0, stream>>>(x, wfrag, dinv, yb);
    k_gather1<<<(N_NODES * 64 + 255) / 256, 256, 0, stream>>>(yb, rowptr, eidx, dinv, b1, hb);

    // layer 2
    k_gemm2<<<(N_NODES + 255) / 256, 256, 0, stream>>>(hb, W2, dinv, y2b);
    k_gather2<<<(N_NODES * 64 + 255) / 256, 256, 0, stream>>>(y2b, rowptr, eidx, dinv, b2, out);
}

// Round 7
// 333.479 us; speedup vs baseline: 2.5296x; 1.0757x over previous
//
#include <hip/hip_runtime.h>
#include <math.h>

#define N_NODES 100000
#define N_EDGES 1600000
#define F_INN   256
#define HID     128
#define NCLS    47

#define SCAN_CHUNK 1024
#define N_SBLOCKS ((N_NODES + SCAN_CHUNK - 1) / SCAN_CHUNK)  // 98

typedef __attribute__((ext_vector_type(8))) short bf16x8;
typedef __attribute__((ext_vector_type(4))) float f32x4;

// ---------------- bf16 helpers (RNE) ----------------
__device__ __forceinline__ unsigned bf16pack(float a, float b) {
    unsigned ua = __float_as_uint(a), ub = __float_as_uint(b);
    ua = (ua + 0x7FFFu + ((ua >> 16) & 1u)) >> 16;
    ub = (ub + 0x7FFFu + ((ub >> 16) & 1u)) >> 16;
    return ua | (ub << 16);
}
__device__ __forceinline__ float2 bf16unpack(unsigned v) {
    return make_float2(__uint_as_float(v << 16), __uint_as_float(v & 0xFFFF0000u));
}
__device__ __forceinline__ float bf16tof(unsigned short u) {
    return __uint_as_float(((unsigned)u) << 16);
}

// ---------------- CSR build ----------------
__global__ void k_init(int* cnt) {
    int i = blockIdx.x * blockDim.x + threadIdx.x;
    if (i < N_NODES) cnt[i] = 0;
}

// count + record within-node rank (the atomic's return value)
__global__ void k_count(const int* __restrict__ dst, int* cnt,
                        unsigned char* __restrict__ rank) {
    int e = blockIdx.x * blockDim.x + threadIdx.x;
    if (e < N_EDGES) rank[e] = (unsigned char)atomicAdd(&cnt[dst[e]], 1);
}

// level-1: per-block (1024 counts) partial sums
__global__ __launch_bounds__(256) void k_scan_part(const int* __restrict__ cnt,
                                                   int* __restrict__ bsum) {
    int b = blockIdx.x, t = threadIdx.x;
    int base = b * SCAN_CHUNK;
    int local = 0;
#pragma unroll
    for (int u = 0; u < 4; u++) {
        int idx = base + u * 256 + t;
        if (idx < N_NODES) local += cnt[idx];
    }
#pragma unroll
    for (int off = 32; off >= 1; off >>= 1) local += __shfl_down(local, off, 64);
    __shared__ int red[4];
    if ((t & 63) == 0) red[t >> 6] = local;
    __syncthreads();
    if (t == 0) bsum[b] = red[0] + red[1] + red[2] + red[3];
}

// level-2: scan the 98 block sums (one small block)
__global__ void k_scan_top(const int* __restrict__ bsum, int* __restrict__ boff) {
    __shared__ int s[128];
    int t = threadIdx.x;
    int v = (t < N_SBLOCKS) ? bsum[t] : 0;
    s[t] = v;
    __syncthreads();
    for (int off = 1; off < 128; off <<= 1) {
        int u = (t >= off) ? s[t - off] : 0;
        __syncthreads();
        s[t] += u;
        __syncthreads();
    }
    if (t < N_SBLOCKS) boff[t] = s[t] - v;  // exclusive
}

// level-3: local scan per block + global offset -> rowptr, dinv
__global__ __launch_bounds__(256) void k_scan_final(const int* __restrict__ cnt,
                                                    const int* __restrict__ boff,
                                                    int* __restrict__ rowptr,
                                                    float* __restrict__ dinv) {
    __shared__ int tsum[256];
    int b = blockIdx.x, t = threadIdx.x;
    int base = b * SCAN_CHUNK + t * 4;
    int c[4];
    int local = 0;
#pragma unroll
    for (int u = 0; u < 4; u++) {
        int idx = base + u;
        c[u] = (idx < N_NODES) ? cnt[idx] : 0;
        local += c[u];
    }
    tsum[t] = local;
    __syncthreads();
    for (int off = 1; off < 256; off <<= 1) {
        int u = (t >= off) ? tsum[t - off] : 0;
        __syncthreads();
        tsum[t] += u;
        __syncthreads();
    }
    int run = boff[b] + tsum[t] - local;
#pragma unroll
    for (int u = 0; u < 4; u++) {
        int idx = base + u;
        if (idx < N_NODES) {
            rowptr[idx] = run;
            dinv[idx] = rsqrtf((float)c[u] + 1.0f);  // +1 self-loop
            run += c[u];
        }
    }
    if (b == 0 && t == 0) rowptr[N_NODES] = N_EDGES;
}

// atomic-free scatter using precomputed rank
__global__ void k_scatter(const int* __restrict__ src, const int* __restrict__ dst,
                          const int* __restrict__ rowptr,
                          const unsigned char* __restrict__ rank,
                          int* __restrict__ eidx) {
    int e = blockIdx.x * blockDim.x + threadIdx.x;
    if (e < N_EDGES) {
        int d = dst[e];
        eidx[rowptr[d] + (int)rank[e]] = src[e];
    }
}

// ---- prep: W1 (256x128 f32) -> MFMA-fragment-ordered bf16 ------------------
// Fragment g = nt*8 + kst (nt: 16-col tile, kst: 32-k step). Lane l of frag g
// holds 8 bf16: W1[kst*32 + (l>>4)*8 + j][nt*16 + (l&15)], j=0..7 (16B).
__global__ __launch_bounds__(256) void k_prep(const float* __restrict__ W1,
                                              uint4* __restrict__ Wf) {
    int g = blockIdx.x * blockDim.x + threadIdx.x;  // 0..4095
    if (g >= 4096) return;
    int l = g & 63;
    int kst = (g >> 6) & 7;
    int nt = g >> 9;
    int n = nt * 16 + (l & 15);
    int kb = kst * 32 + ((l >> 4) << 3);
    float v[8];
#pragma unroll
    for (int j = 0; j < 8; j++) v[j] = W1[(size_t)(kb + j) * HID + n];
    uint4 o;
    o.x = bf16pack(v[0], v[1]);
    o.y = bf16pack(v[2], v[3]);
    o.z = bf16pack(v[4], v[5]);
    o.w = bf16pack(v[6], v[7]);
    Wf[g] = o;
}

// ---------------- GEMM1 (MFMA): Yb = bf16((X @ W1) * dinv[row]) -------------
// 128x128 tile, 4 waves (2x2), 16x16x32 bf16 MFMA, K=256 in 8 steps.
__global__ __launch_bounds__(256) void k_gemm1(const float* __restrict__ X,
                                               const uint4* __restrict__ Wf,
                                               const float* __restrict__ dinv,
                                               unsigned* __restrict__ Yb) {
    __shared__ __align__(16) unsigned short xs[128 * 32];
    int tid = threadIdx.x;
    int lane = tid & 63, w = tid >> 6;
    int wr = w >> 1, wc = w & 1;
    int row0 = blockIdx.x * 128;

    f32x4 acc[4][4];  // [fm][fn]
#pragma unroll
    for (int i = 0; i < 4; i++)
#pragma unroll
        for (int j = 0; j < 4; j++) acc[i][j] = (f32x4){0.f, 0.f, 0.f, 0.f};

    for (int ks = 0; ks < 8; ks++) {
        int k0 = ks * 32;
        // stage X tile [128 rows][32 k] f32 -> bf16 (coalesced, conflict-free)
#pragma unroll
        for (int u = 0; u < 4; u++) {
            int slot = u * 256 + tid;          // 0..1023
            int r = slot >> 3, c4 = slot & 7;  // row, float4-slot
            int rr = min(row0 + r, N_NODES - 1);
            float4 v = *(const float4*)&X[(size_t)rr * F_INN + k0 + c4 * 4];
            uint2 p;
            p.x = bf16pack(v.x, v.y);
            p.y = bf16pack(v.z, v.w);
            *(uint2*)&xs[r * 32 + c4 * 4] = p;
        }
        // B-frags straight from global (64KB, L2-hot)
        bf16x8 bfr[4];
#pragma unroll
        for (int fn = 0; fn < 4; fn++) {
            uint4 t = Wf[((wc * 4 + fn) * 8 + ks) * 64 + lane];
            bfr[fn] = *(bf16x8*)&t;
        }
        __syncthreads();
        bf16x8 afr[4];
#pragma unroll
        for (int fm = 0; fm < 4; fm++) {
            int r = wr * 64 + fm * 16 + (lane & 15);
            afr[fm] = *(const bf16x8*)&xs[r * 32 + ((lane >> 4) << 3)];
        }
#pragma unroll
        for (int fm = 0; fm < 4; fm++)
#pragma unroll
            for (int fn = 0; fn < 4; fn++)
                acc[fm][fn] = __builtin_amdgcn_mfma_f32_16x16x32_bf16(
                    bfr[fn], afr[fm], acc[fm][fn], 0, 0, 0);
        __syncthreads();
    }
    // epilogue: regs sweep n (first operand = W), lane&15 = row within fm-tile
#pragma unroll
    for (int fm = 0; fm < 4; fm++) {
        int row = row0 + wr * 64 + fm * 16 + (lane & 15);
        if (row < N_NODES) {
            float s = dinv[row];
            unsigned short* yrow = (unsigned short*)Yb + (size_t)row * 128;
#pragma unroll
            for (int fn = 0; fn < 4; fn++) {
                int col = wc * 64 + fn * 16 + ((lane >> 4) << 2);
                uint2 p;
                p.x = bf16pack(acc[fm][fn][0] * s, acc[fm][fn][1] * s);
                p.y = bf16pack(acc[fm][fn][2] * s, acc[fm][fn][3] * s);
                *(uint2*)&yrow[col] = p;
            }
        }
    }
}

// ------------- gather1: Hb = bf16(relu(dinv[i]*(y_i + sum_j y_j) + b1)) -----
__global__ __launch_bounds__(256) void k_gather1(const unsigned* __restrict__ Yb,
                                                 const int* __restrict__ rowptr,
                                                 const int* __restrict__ eidx,
                                                 const float* __restrict__ dinv,
                                                 const float* __restrict__ b1,
                                                 unsigned* __restrict__ Hb) {
    int wave = (blockIdx.x * blockDim.x + threadIdx.x) >> 6;
    int lane = threadIdx.x & 63;
    if (wave >= N_NODES) return;
    float2 acc = bf16unpack(Yb[(size_t)wave * 64 + lane]);  // self-loop
    int beg = rowptr[wave], end = rowptr[wave + 1];
    int e = beg;
    for (; e + 3 < end; e += 4) {
        int j0 = eidx[e], j1 = eidx[e + 1], j2 = eidx[e + 2], j3 = eidx[e + 3];
        unsigned v0 = Yb[(size_t)j0 * 64 + lane];
        unsigned v1 = Yb[(size_t)j1 * 64 + lane];
        unsigned v2 = Yb[(size_t)j2 * 64 + lane];
        unsigned v3 = Yb[(size_t)j3 * 64 + lane];
        float2 a = bf16unpack(v0), b = bf16unpack(v1);
        float2 c = bf16unpack(v2), d = bf16unpack(v3);
        acc.x += (a.x + b.x) + (c.x + d.x);
        acc.y += (a.y + b.y) + (c.y + d.y);
    }
    for (; e < end; e++) {
        float2 a = bf16unpack(Yb[(size_t)eidx[e] * 64 + lane]);
        acc.x += a.x; acc.y += a.y;
    }
    float s = dinv[wave];
    float2 b = ((const float2*)b1)[lane];
    float ox = fmaxf(acc.x * s + b.x, 0.f);
    float oy = fmaxf(acc.y * s + b.y, 0.f);
    Hb[(size_t)wave * 64 + lane] = bf16pack(ox, oy);
}

// ------------- GEMM2: Y2b = bf16((H @ W2) * dinv[row])  (N x 128 @ 128 x 47)
__global__ __launch_bounds__(256) void k_gemm2(const unsigned* __restrict__ Hb,
                                               const float* __restrict__ W2,
                                               const float* __restrict__ dinv,
                                               unsigned short* __restrict__ Y2b) {
    __shared__ __align__(16) float ws[128][48];
    int tid = threadIdx.x;
    for (int idx = tid; idx < 128 * 48; idx += 256) {
        int k = idx / 48, c = idx - k * 48;
        ws[k][c] = (c < NCLS) ? W2[k * NCLS + c] : 0.f;
    }
    __syncthreads();
    int row = blockIdx.x * 256 + tid;
    if (row >= N_NODES) return;
    float4 acc[12];
#pragma unroll
    for (int i = 0; i < 12; i++) acc[i] = make_float4(0.f, 0.f, 0.f, 0.f);
    const uint4* h4 = (const uint4*)(Hb + (size_t)row * 64);
    for (int kq = 0; kq < 16; kq++) {
        uint4 hv = h4[kq];
        float f[8];
        float2 f0 = bf16unpack(hv.x), f1 = bf16unpack(hv.y);
        float2 f2 = bf16unpack(hv.z), f3 = bf16unpack(hv.w);
        f[0] = f0.x; f[1] = f0.y; f[2] = f1.x; f[3] = f1.y;
        f[4] = f2.x; f[5] = f2.y; f[6] = f3.x; f[7] = f3.y;
#pragma unroll
        for (int u = 0; u < 8; u++) {
            float xv = f[u];
            int k = kq * 8 + u;
#pragma unroll
            for (int c = 0; c < 12; c++) {
                float4 w = *(const float4*)&ws[k][c * 4];
                acc[c].x += xv * w.x; acc[c].y += xv * w.y;
                acc[c].z += xv * w.z; acc[c].w += xv * w.w;
            }
        }
    }
    float s = dinv[row];
#pragma unroll
    for (int c = 0; c < 12; c++) {
        uint2 o;
        o.x = bf16pack(acc[c].x * s, acc[c].y * s);
        o.y = bf16pack(acc[c].z * s, acc[c].w * s);
        *(uint2*)((char*)Y2b + ((size_t)row * 48 + c * 4) * 2) = o;
    }
}

// --- gather2 + fused log_softmax: Out = logsoftmax(dinv*(y2_i+sum y2_j)+b2) --
__global__ __launch_bounds__(256) void k_gather2(const unsigned short* __restrict__ Y2b,
                                                 const int* __restrict__ rowptr,
                                                 const int* __restrict__ eidx,
                                                 const float* __restrict__ dinv,
                                                 const float* __restrict__ b2,
                                                 float* __restrict__ Out) {
    int wave = (blockIdx.x * blockDim.x + threadIdx.x) >> 6;
    int lane = threadIdx.x & 63;
    if (wave >= N_NODES) return;
    bool act = lane < NCLS;
    float acc = 0.f;
    if (act) acc = bf16tof(Y2b[(size_t)wave * 48 + lane]);
    int beg = rowptr[wave], end = rowptr[wave + 1];
    int e = beg;
    for (; e + 3 < end; e += 4) {
        int j0 = eidx[e], j1 = eidx[e + 1], j2 = eidx[e + 2], j3 = eidx[e + 3];
        float v0 = 0.f, v1 = 0.f, v2 = 0.f, v3 = 0.f;
        if (act) {
            v0 = bf16tof(Y2b[(size_t)j0 * 48 + lane]);
            v1 = bf16tof(Y2b[(size_t)j1 * 48 + lane]);
            v2 = bf16tof(Y2b[(size_t)j2 * 48 + lane]);
            v3 = bf16tof(Y2b[(size_t)j3 * 48 + lane]);
        }
        acc += (v0 + v1) + (v2 + v3);
    }
    for (; e < end; e++) {
        if (act) acc += bf16tof(Y2b[(size_t)eidx[e] * 48 + lane]);
    }
    float v = act ? (acc * dinv[wave] + b2[lane]) : -INFINITY;
    // fused log_softmax over 47 lanes
    float m = v;
#pragma unroll
    for (int off = 32; off >= 1; off >>= 1) m = fmaxf(m, __shfl_xor(m, off, 64));
    float ex = act ? __expf(v - m) : 0.f;
    float ssum = ex;
#pragma unroll
    for (int off = 32; off >= 1; off >>= 1) ssum += __shfl_xor(ssum, off, 64);
    float l = __logf(ssum);
    if (act) Out[(size_t)wave * NCLS + lane] = v - m - l;
}

extern "C" void kernel_launch(void* const* d_in, const int* in_sizes, int n_in,
                              void* d_out, int out_size, void* d_ws, size_t ws_size,
                              hipStream_t stream) {
    const float* x   = (const float*)d_in[0];
    const int*   ei  = (const int*)d_in[1];
    const float* W1  = (const float*)d_in[2];
    const float* b1  = (const float*)d_in[3];
    const float* W2  = (const float*)d_in[4];
    const float* b2  = (const float*)d_in[5];
    float* out = (float*)d_out;

    const int* src = ei;             // edge_index[0]
    const int* dst = ei + N_EDGES;   // edge_index[1]

    char* ws = (char*)d_ws;
    unsigned*       yb   = (unsigned*)      (ws + 0);          // N*64 u32  (25.6 MB)
    unsigned*       hb   = (unsigned*)      (ws + 25600000);   // N*64 u32  (25.6 MB)
    unsigned short* y2b  = (unsigned short*)(ws + 51200000);   // N*48 u16  (9.6 MB)
    float*          dinv = (float*)         (ws + 60800000);   // N f32
    int*            cnt  = (int*)           (ws + 61200000);   // N int
    int*            rowptr=(int*)           (ws + 61600000);   // N+1 int
    int*            eidx = (int*)           (ws + 62000016);   // E int (6.4 MB)
    int*            bsum = (int*)           (ws + 68400016);   // 98 int
    int*            boff = (int*)           (ws + 68401040);   // 98 int
    unsigned char*  rank = (unsigned char*) (ws + 68402064);   // E u8 (1.6 MB)
    uint4*          wfrag= (uint4*)         (ws + 70002064);   // 64 KB

    // CSR build
    k_init<<<(N_NODES + 255) / 256, 256, 0, stream>>>(cnt);
    k_count<<<(N_EDGES + 255) / 256, 256, 0, stream>>>(dst, cnt, rank);
    k_scan_part<<<N_SBLOCKS, 256, 0, stream>>>(cnt, bsum);
    k_scan_top<<<1, 128, 0, stream>>>(bsum, boff);
    k_scan_final<<<N_SBLOCKS, 256, 0, stream>>>(cnt, boff, rowptr, dinv);
    k_scatter<<<(N_EDGES + 255) / 256, 256, 0, stream>>>(src, dst, rowptr, rank, eidx);

    // W1 -> fragment-ordered bf16
    k_prep<<<16, 256, 0, stream>>>(W1, wfrag);

    // layer 1
    k_gemm1<<<(N_NODES + 127) / 128, 256, 0, stream>>>(x, wfrag, dinv, yb);
    k_gather1<<<(N_NODES * 64 + 255) / 256, 256, 0, stream>>>(yb, rowptr, eidx, dinv, b1, hb);

    // layer 2
    k_gemm2<<<(N_NODES + 255) / 256, 256, 0, stream>>>(hb, W2, dinv, y2b);
    k_gather2<<<(N_NODES * 64 + 255) / 256, 256, 0, stream>>>(y2b, rowptr, eidx, dinv, b2, out);
}

// Round 8
// 328.906 us; speedup vs baseline: 2.5647x; 1.0139x over previous
//
#include <hip/hip_runtime.h>
#include <math.h>

#define N_NODES 100000
#define N_EDGES 1600000
#define F_INN   256
#define HID     128
#define NCLS    47

#define SCAN_CHUNK 1024
#define N_SBLOCKS ((N_NODES + SCAN_CHUNK - 1) / SCAN_CHUNK)  // 98

typedef __attribute__((ext_vector_type(8))) short bf16x8;
typedef __attribute__((ext_vector_type(4))) float f32x4;

// ---------------- bf16 helpers (RNE) ----------------
__device__ __forceinline__ unsigned bf16pack(float a, float b) {
    unsigned ua = __float_as_uint(a), ub = __float_as_uint(b);
    ua = (ua + 0x7FFFu + ((ua >> 16) & 1u)) >> 16;
    ub = (ub + 0x7FFFu + ((ub >> 16) & 1u)) >> 16;
    return ua | (ub << 16);
}
__device__ __forceinline__ float2 bf16unpack(unsigned v) {
    return make_float2(__uint_as_float(v << 16), __uint_as_float(v & 0xFFFF0000u));
}
__device__ __forceinline__ float bf16tof(unsigned short u) {
    return __uint_as_float(((unsigned)u) << 16);
}

// ---------------- CSR build ----------------
__global__ void k_init(int* cnt) {
    int i = blockIdx.x * blockDim.x + threadIdx.x;
    if (i < N_NODES) cnt[i] = 0;
}

// count + record within-node rank (the atomic's return value)
__global__ void k_count(const int* __restrict__ dst, int* cnt,
                        unsigned char* __restrict__ rank) {
    int e = blockIdx.x * blockDim.x + threadIdx.x;
    if (e < N_EDGES) rank[e] = (unsigned char)atomicAdd(&cnt[dst[e]], 1);
}

// level-1: per-block (1024 counts) partial sums
__global__ __launch_bounds__(256) void k_scan_part(const int* __restrict__ cnt,
                                                   int* __restrict__ bsum) {
    int b = blockIdx.x, t = threadIdx.x;
    int base = b * SCAN_CHUNK;
    int local = 0;
#pragma unroll
    for (int u = 0; u < 4; u++) {
        int idx = base + u * 256 + t;
        if (idx < N_NODES) local += cnt[idx];
    }
#pragma unroll
    for (int off = 32; off >= 1; off >>= 1) local += __shfl_down(local, off, 64);
    __shared__ int red[4];
    if ((t & 63) == 0) red[t >> 6] = local;
    __syncthreads();
    if (t == 0) bsum[b] = red[0] + red[1] + red[2] + red[3];
}

// level-2: scan the 98 block sums (one small block)
__global__ void k_scan_top(const int* __restrict__ bsum, int* __restrict__ boff) {
    __shared__ int s[128];
    int t = threadIdx.x;
    int v = (t < N_SBLOCKS) ? bsum[t] : 0;
    s[t] = v;
    __syncthreads();
    for (int off = 1; off < 128; off <<= 1) {
        int u = (t >= off) ? s[t - off] : 0;
        __syncthreads();
        s[t] += u;
        __syncthreads();
    }
    if (t < N_SBLOCKS) boff[t] = s[t] - v;  // exclusive
}

// level-3: local scan per block + global offset -> rowptr, dinv
__global__ __launch_bounds__(256) void k_scan_final(const int* __restrict__ cnt,
                                                    const int* __restrict__ boff,
                                                    int* __restrict__ rowptr,
                                                    float* __restrict__ dinv) {
    __shared__ int tsum[256];
    int b = blockIdx.x, t = threadIdx.x;
    int base = b * SCAN_CHUNK + t * 4;
    int c[4];
    int local = 0;
#pragma unroll
    for (int u = 0; u < 4; u++) {
        int idx = base + u;
        c[u] = (idx < N_NODES) ? cnt[idx] : 0;
        local += c[u];
    }
    tsum[t] = local;
    __syncthreads();
    for (int off = 1; off < 256; off <<= 1) {
        int u = (t >= off) ? tsum[t - off] : 0;
        __syncthreads();
        tsum[t] += u;
        __syncthreads();
    }
    int run = boff[b] + tsum[t] - local;
#pragma unroll
    for (int u = 0; u < 4; u++) {
        int idx = base + u;
        if (idx < N_NODES) {
            rowptr[idx] = run;
            dinv[idx] = rsqrtf((float)c[u] + 1.0f);  // +1 self-loop
            run += c[u];
        }
    }
    if (b == 0 && t == 0) rowptr[N_NODES] = N_EDGES;
}

// atomic-free scatter using precomputed rank
__global__ void k_scatter(const int* __restrict__ src, const int* __restrict__ dst,
                          const int* __restrict__ rowptr,
                          const unsigned char* __restrict__ rank,
                          int* __restrict__ eidx) {
    int e = blockIdx.x * blockDim.x + threadIdx.x;
    if (e < N_EDGES) {
        int d = dst[e];
        eidx[rowptr[d] + (int)rank[e]] = src[e];
    }
}

// ---- prep: W1 (256x128 f32) -> MFMA-fragment-ordered bf16 ------------------
// Fragment g = nt*8 + kst (nt: 16-col tile, kst: 32-k step). Lane l of frag g
// holds 8 bf16: W1[kst*32 + (l>>4)*8 + j][nt*16 + (l&15)], j=0..7 (16B).
__global__ __launch_bounds__(256) void k_prep(const float* __restrict__ W1,
                                              uint4* __restrict__ Wf) {
    int g = blockIdx.x * blockDim.x + threadIdx.x;  // 0..4095
    if (g >= 4096) return;
    int l = g & 63;
    int kst = (g >> 6) & 7;
    int nt = g >> 9;
    int n = nt * 16 + (l & 15);
    int kb = kst * 32 + ((l >> 4) << 3);
    float v[8];
#pragma unroll
    for (int j = 0; j < 8; j++) v[j] = W1[(size_t)(kb + j) * HID + n];
    uint4 o;
    o.x = bf16pack(v[0], v[1]);
    o.y = bf16pack(v[2], v[3]);
    o.z = bf16pack(v[4], v[5]);
    o.w = bf16pack(v[6], v[7]);
    Wf[g] = o;
}

// ---------------- GEMM1 (MFMA): Yb = bf16((X @ W1) * dinv[row]) -------------
// 128x128 tile, 4 waves (2x2), 16x16x32 bf16 MFMA, K=256 in 8 steps.
__global__ __launch_bounds__(256) void k_gemm1(const float* __restrict__ X,
                                               const uint4* __restrict__ Wf,
                                               const float* __restrict__ dinv,
                                               unsigned* __restrict__ Yb) {
    __shared__ __align__(16) unsigned short xs[128 * 32];
    int tid = threadIdx.x;
    int lane = tid & 63, w = tid >> 6;
    int wr = w >> 1, wc = w & 1;
    int row0 = blockIdx.x * 128;

    f32x4 acc[4][4];  // [fm][fn]
#pragma unroll
    for (int i = 0; i < 4; i++)
#pragma unroll
        for (int j = 0; j < 4; j++) acc[i][j] = (f32x4){0.f, 0.f, 0.f, 0.f};

    for (int ks = 0; ks < 8; ks++) {
        int k0 = ks * 32;
        // stage X tile [128 rows][32 k] f32 -> bf16 (coalesced, conflict-free)
#pragma unroll
        for (int u = 0; u < 4; u++) {
            int slot = u * 256 + tid;          // 0..1023
            int r = slot >> 3, c4 = slot & 7;  // row, float4-slot
            int rr = min(row0 + r, N_NODES - 1);
            float4 v = *(const float4*)&X[(size_t)rr * F_INN + k0 + c4 * 4];
            uint2 p;
            p.x = bf16pack(v.x, v.y);
            p.y = bf16pack(v.z, v.w);
            *(uint2*)&xs[r * 32 + c4 * 4] = p;
        }
        // B-frags straight from global (64KB, L2-hot)
        bf16x8 bfr[4];
#pragma unroll
        for (int fn = 0; fn < 4; fn++) {
            uint4 t = Wf[((wc * 4 + fn) * 8 + ks) * 64 + lane];
            bfr[fn] = *(bf16x8*)&t;
        }
        __syncthreads();
        bf16x8 afr[4];
#pragma unroll
        for (int fm = 0; fm < 4; fm++) {
            int r = wr * 64 + fm * 16 + (lane & 15);
            afr[fm] = *(const bf16x8*)&xs[r * 32 + ((lane >> 4) << 3)];
        }
#pragma unroll
        for (int fm = 0; fm < 4; fm++)
#pragma unroll
            for (int fn = 0; fn < 4; fn++)
                acc[fm][fn] = __builtin_amdgcn_mfma_f32_16x16x32_bf16(
                    bfr[fn], afr[fm], acc[fm][fn], 0, 0, 0);
        __syncthreads();
    }
    // epilogue: regs sweep n (first operand = W), lane&15 = row within fm-tile
#pragma unroll
    for (int fm = 0; fm < 4; fm++) {
        int row = row0 + wr * 64 + fm * 16 + (lane & 15);
        if (row < N_NODES) {
            float s = dinv[row];
            unsigned short* yrow = (unsigned short*)Yb + (size_t)row * 128;
#pragma unroll
            for (int fn = 0; fn < 4; fn++) {
                int col = wc * 64 + fn * 16 + ((lane >> 4) << 2);
                uint2 p;
                p.x = bf16pack(acc[fm][fn][0] * s, acc[fm][fn][1] * s);
                p.y = bf16pack(acc[fm][fn][2] * s, acc[fm][fn][3] * s);
                *(uint2*)&yrow[col] = p;
            }
        }
    }
}

// ------------- gather1: Hb = bf16(relu(dinv[i]*(y_i + sum_j y_j) + b1)) -----
__global__ __launch_bounds__(256) void k_gather1(const unsigned* __restrict__ Yb,
                                                 const int* __restrict__ rowptr,
                                                 const int* __restrict__ eidx,
                                                 const float* __restrict__ dinv,
                                                 const float* __restrict__ b1,
                                                 unsigned* __restrict__ Hb) {
    int wave = (blockIdx.x * blockDim.x + threadIdx.x) >> 6;
    int lane = threadIdx.x & 63;
    if (wave >= N_NODES) return;
    float2 acc = bf16unpack(Yb[(size_t)wave * 64 + lane]);  // self-loop
    int beg = rowptr[wave], end = rowptr[wave + 1];
    int e = beg;
    for (; e + 7 < end; e += 8) {
        int j[8];
#pragma unroll
        for (int u = 0; u < 8; u++) j[u] = eidx[e + u];
        unsigned v[8];
#pragma unroll
        for (int u = 0; u < 8; u++) v[u] = Yb[(size_t)j[u] * 64 + lane];
        float sx = 0.f, sy = 0.f;
#pragma unroll
        for (int u = 0; u < 8; u++) {
            float2 a = bf16unpack(v[u]);
            sx += a.x; sy += a.y;
        }
        acc.x += sx; acc.y += sy;
    }
    for (; e < end; e++) {
        float2 a = bf16unpack(Yb[(size_t)eidx[e] * 64 + lane]);
        acc.x += a.x; acc.y += a.y;
    }
    float s = dinv[wave];
    float2 b = ((const float2*)b1)[lane];
    float ox = fmaxf(acc.x * s + b.x, 0.f);
    float oy = fmaxf(acc.y * s + b.y, 0.f);
    Hb[(size_t)wave * 64 + lane] = bf16pack(ox, oy);
}

// ------------- GEMM2: Y2b = bf16((H @ W2) * dinv[row]), row stride 64 u16 ---
__global__ __launch_bounds__(256) void k_gemm2(const unsigned* __restrict__ Hb,
                                               const float* __restrict__ W2,
                                               const float* __restrict__ dinv,
                                               unsigned short* __restrict__ Y2b) {
    __shared__ __align__(16) float ws[128][48];
    int tid = threadIdx.x;
    for (int idx = tid; idx < 128 * 48; idx += 256) {
        int k = idx / 48, c = idx - k * 48;
        ws[k][c] = (c < NCLS) ? W2[k * NCLS + c] : 0.f;
    }
    __syncthreads();
    int row = blockIdx.x * 256 + tid;
    if (row >= N_NODES) return;
    float4 acc[12];
#pragma unroll
    for (int i = 0; i < 12; i++) acc[i] = make_float4(0.f, 0.f, 0.f, 0.f);
    const uint4* h4 = (const uint4*)(Hb + (size_t)row * 64);
    for (int kq = 0; kq < 16; kq++) {
        uint4 hv = h4[kq];
        float f[8];
        float2 f0 = bf16unpack(hv.x), f1 = bf16unpack(hv.y);
        float2 f2 = bf16unpack(hv.z), f3 = bf16unpack(hv.w);
        f[0] = f0.x; f[1] = f0.y; f[2] = f1.x; f[3] = f1.y;
        f[4] = f2.x; f[5] = f2.y; f[6] = f3.x; f[7] = f3.y;
#pragma unroll
        for (int u = 0; u < 8; u++) {
            float xv = f[u];
            int k = kq * 8 + u;
#pragma unroll
            for (int c = 0; c < 12; c++) {
                float4 w = *(const float4*)&ws[k][c * 4];
                acc[c].x += xv * w.x; acc[c].y += xv * w.y;
                acc[c].z += xv * w.z; acc[c].w += xv * w.w;
            }
        }
    }
    float s = dinv[row];
#pragma unroll
    for (int c = 0; c < 12; c++) {
        uint2 o;
        o.x = bf16pack(acc[c].x * s, acc[c].y * s);
        o.y = bf16pack(acc[c].z * s, acc[c].w * s);
        *(uint2*)((char*)Y2b + ((size_t)row * 64 + c * 4) * 2) = o;
    }
}

// --- gather2 + fused log_softmax: Out = logsoftmax(dinv*(y2_i+sum y2_j)+b2) --
__global__ __launch_bounds__(256) void k_gather2(const unsigned short* __restrict__ Y2b,
                                                 const int* __restrict__ rowptr,
                                                 const int* __restrict__ eidx,
                                                 const float* __restrict__ dinv,
                                                 const float* __restrict__ b2,
                                                 float* __restrict__ Out) {
    int wave = (blockIdx.x * blockDim.x + threadIdx.x) >> 6;
    int lane = threadIdx.x & 63;
    if (wave >= N_NODES) return;
    bool act = lane < NCLS;
    float acc = bf16tof(Y2b[(size_t)wave * 64 + lane]);  // lanes>=47 read pad
    int beg = rowptr[wave], end = rowptr[wave + 1];
    int e = beg;
    for (; e + 7 < end; e += 8) {
        int j[8];
#pragma unroll
        for (int u = 0; u < 8; u++) j[u] = eidx[e + u];
        float v[8];
#pragma unroll
        for (int u = 0; u < 8; u++) v[u] = bf16tof(Y2b[(size_t)j[u] * 64 + lane]);
        acc += ((v[0] + v[1]) + (v[2] + v[3])) + ((v[4] + v[5]) + (v[6] + v[7]));
    }
    for (; e < end; e++) {
        acc += bf16tof(Y2b[(size_t)eidx[e] * 64 + lane]);
    }
    float v = act ? (acc * dinv[wave] + b2[lane]) : -INFINITY;
    // fused log_softmax over 47 lanes
    float m = v;
#pragma unroll
    for (int off = 32; off >= 1; off >>= 1) m = fmaxf(m, __shfl_xor(m, off, 64));
    float ex = act ? __expf(v - m) : 0.f;
    float ssum = ex;
#pragma unroll
    for (int off = 32; off >= 1; off >>= 1) ssum += __shfl_xor(ssum, off, 64);
    float l = __logf(ssum);
    if (act) Out[(size_t)wave * NCLS + lane] = v - m - l;
}

extern "C" void kernel_launch(void* const* d_in, const int* in_sizes, int n_in,
                              void* d_out, int out_size, void* d_ws, size_t ws_size,
                              hipStream_t stream) {
    const float* x   = (const float*)d_in[0];
    const int*   ei  = (const int*)d_in[1];
    const float* W1  = (const float*)d_in[2];
    const float* b1  = (const float*)d_in[3];
    const float* W2  = (const float*)d_in[4];
    const float* b2  = (const float*)d_in[5];
    float* out = (float*)d_out;

    const int* src = ei;             // edge_index[0]
    const int* dst = ei + N_EDGES;   // edge_index[1]

    char* ws = (char*)d_ws;
    unsigned*       yb   = (unsigned*)      (ws + 0);          // N*64 u32  (25.6 MB)
    unsigned*       hb   = (unsigned*)      (ws + 25600000);   // N*64 u32  (25.6 MB)
    unsigned short* y2b  = (unsigned short*)(ws + 51200000);   // N*64 u16  (12.8 MB)
    float*          dinv = (float*)         (ws + 64000000);   // N f32
    int*            cnt  = (int*)           (ws + 64400000);   // N int
    int*            rowptr=(int*)           (ws + 64800000);   // N+1 int
    int*            eidx = (int*)           (ws + 65200016);   // E int (6.4 MB)
    int*            bsum = (int*)           (ws + 71600016);   // 98 int
    int*            boff = (int*)           (ws + 71601040);   // 98 int
    unsigned char*  rank = (unsigned char*) (ws + 71602064);   // E u8 (1.6 MB)
    uint4*          wfrag= (uint4*)         (ws + 73202064);   // 64 KB

    // CSR build
    k_init<<<(N_NODES + 255) / 256, 256, 0, stream>>>(cnt);
    k_count<<<(N_EDGES + 255) / 256, 256, 0, stream>>>(dst, cnt, rank);
    k_scan_part<<<N_SBLOCKS, 256, 0, stream>>>(cnt, bsum);
    k_scan_top<<<1, 128, 0, stream>>>(bsum, boff);
    k_scan_final<<<N_SBLOCKS, 256, 0, stream>>>(cnt, boff, rowptr, dinv);
    k_scatter<<<(N_EDGES + 255) / 256, 256, 0, stream>>>(src, dst, rowptr, rank, eidx);

    // W1 -> fragment-ordered bf16
    k_prep<<<16, 256, 0, stream>>>(W1, wfrag);

    // layer 1
    k_gemm1<<<(N_NODES + 127) / 128, 256, 0, stream>>>(x, wfrag, dinv, yb);
    k_gather1<<<(N_NODES * 64 + 255) / 256, 256, 0, stream>>>(yb, rowptr, eidx, dinv, b1, hb);

    // layer 2
    k_gemm2<<<(N_NODES + 255) / 256, 256, 0, stream>>>(hb, W2, dinv, y2b);
    k_gather2<<<(N_NODES * 64 + 255) / 256, 256, 0, stream>>>(y2b, rowptr, eidx, dinv, b2, out);
}